// Round 1
// baseline (27759.363 us; speedup 1.0000x reference)
//
#include <hip/hip_runtime.h>
#include <math.h>

#define DEV __device__ __forceinline__

constexpr int BATCH = 2;
constexpr int L0 = 4096;
constexpr int LS1 = 2048;   // after conv1 (stride2)
constexpr int LS2 = 1024;   // after conv2 (stride2) and conv3
constexpr int SEQ = 1024;
constexpr int DM = 768;
constexpr int NH = 24;
constexpr int HD = 64;
constexpr int DI = 1536;
constexpr int DSTATE = 128;
constexpr int CDIM = 1792;   // DI + 2*DSTATE
constexpr int PDIM = 3352;   // 2*DI + 2*DSTATE + NH
constexpr int CHUNKC = 256;
constexpr int NCH = 4;       // SEQ / CHUNK
constexpr int NLAYER = 24;
constexpr float EPSF = 1e-5f;

DEV float sigmoidf_(float x){ return 1.f/(1.f+expf(-x)); }
DEV float siluf_(float x){ return x*sigmoidf_(x); }
DEV float geluf_(float x){ return 0.5f*x*(1.f+erff(x*0.70710678118654752440f)); }
DEV float softplusf_(float x){ return fmaxf(x,0.f) + log1pf(expf(-fabsf(x))); }

DEV float block_sum_256(float v, float* red4){
  #pragma unroll
  for (int o=32;o>0;o>>=1) v += __shfl_down(v,o,64);
  int tid = threadIdx.x;
  __syncthreads();
  if ((tid&63)==0) red4[tid>>6]=v;
  __syncthreads();
  return red4[0]+red4[1]+red4[2]+red4[3];
}

// ---------------- stem ----------------
__global__ __launch_bounds__(256) void conv_stem1(const float* __restrict__ x,
    const float* __restrict__ w, const float* __restrict__ bias,
    const float* __restrict__ g, const float* __restrict__ bb,
    const float* __restrict__ mn, const float* __restrict__ vr,
    float* __restrict__ out){
  int idx = blockIdx.x*256+threadIdx.x;
  if (idx >= BATCH*192*LS1) return;
  int lo = idx & (LS1-1);
  int co = (idx >> 11) % 192;
  int b  = idx / (192*LS1);
  float s = bias[co];
  const float* wr = w + co*60;
  #pragma unroll
  for (int ci=0; ci<12; ci++){
    const float* xr = x + ((size_t)(b*12+ci))*L0;
    #pragma unroll
    for (int k=0;k<5;k++){
      int li = lo*2 + k - 2;
      if (li>=0 && li<L0) s += wr[ci*5+k]*xr[li];
    }
  }
  s = geluf_(s);
  s = (s-mn[co])*(g[co]*rsqrtf(vr[co]+EPSF)) + bb[co];
  out[idx] = s;    // layout (b, co, lo)
}

__global__ __launch_bounds__(256) void conv_stem2(const float* __restrict__ x,
    const float* __restrict__ w, const float* __restrict__ bias,
    const float* __restrict__ g, const float* __restrict__ bb,
    const float* __restrict__ mn, const float* __restrict__ vr,
    float* __restrict__ out){
  int idx = blockIdx.x*256+threadIdx.x;
  if (idx >= BATCH*384*LS2) return;
  int lo = idx & (LS2-1);
  int co = (idx >> 10) % 384;
  int b  = idx / (384*LS2);
  float s = bias[co];
  const float* wr = w + co*(192*3);
  const float* xb = x + (size_t)b*192*LS1;
  for (int ci=0; ci<192; ci++){
    const float* base = xb + ci*LS1;
    int l2 = lo*2;
    s += wr[ci*3+1]*base[l2];       // li = lo*2 (always valid)
    s += wr[ci*3+2]*base[l2+1];     // li = lo*2+1 <= 2047 (always valid)
    if (lo>0) s += wr[ci*3]*base[l2-1];
  }
  s = geluf_(s);
  s = (s-mn[co])*(g[co]*rsqrtf(vr[co]+EPSF)) + bb[co];
  out[idx] = s;   // layout (b, co, lo)
}

// conv3 writes transposed into h: (b, l, co)
__global__ __launch_bounds__(256) void conv_stem3(const float* __restrict__ x,
    const float* __restrict__ w, const float* __restrict__ bias,
    const float* __restrict__ g, const float* __restrict__ bb,
    const float* __restrict__ mn, const float* __restrict__ vr,
    float* __restrict__ h){
  int idx = blockIdx.x*256+threadIdx.x;
  if (idx >= BATCH*LS2*768) return;
  int co = idx % 768;
  int lo = (idx/768) % LS2;
  int b  = idx / (768*LS2);
  float s = bias[co];
  const float* wr = w + (size_t)co*384*3;
  const float* xb = x + (size_t)b*384*LS2;
  for (int ci=0; ci<384; ci++){
    const float* xr = xb + ci*LS2 + lo;
    s += wr[ci*3+1]*xr[0];
    if (lo>0)     s += wr[ci*3]*xr[-1];
    if (lo<LS2-1) s += wr[ci*3+2]*xr[1];
  }
  s = geluf_(s);
  s = (s-mn[co])*(g[co]*rsqrtf(vr[co]+EPSF)) + bb[co];
  h[((size_t)(b*SEQ+lo))*DM + co] = s;
}

// ---------------- rmsnorm (D=768) ----------------
__global__ __launch_bounds__(256) void rmsnorm768(const float* __restrict__ in,
    const float* __restrict__ w, float* __restrict__ out){
  int row = blockIdx.x;
  const float* p = in + (size_t)row*DM;
  float v0[3]; float ss=0.f;
  #pragma unroll
  for (int t=0;t<3;t++){ float q = p[threadIdx.x + t*256]; v0[t]=q; ss+=q*q; }
  __shared__ float red[4];
  float tot = block_sum_256(ss, red);
  float sc = rsqrtf(tot*(1.f/DM) + EPSF);
  #pragma unroll
  for (int t=0;t<3;t++){
    int d = threadIdx.x + t*256;
    out[(size_t)row*DM + d] = v0[t]*sc*w[d];
  }
}

// ---------------- fp32 GEMM: C[M,N] (+)= A[M,K] @ W[K,N], 64x64 tile ----------
// M must be a multiple of 64, K multiple of 16. N arbitrary (guarded).
template<int ACCUM>
__global__ __launch_bounds__(256) void gemm_f32(const float* __restrict__ A,
    const float* __restrict__ W, float* __restrict__ C, int M, int N, int K){
  __shared__ float As[16][64];
  __shared__ float Bs[16][64];
  int tid = threadIdx.x;
  int tx = tid & 15, ty = tid >> 4;
  int mBase = blockIdx.y * 64, nBase = blockIdx.x * 64;
  float acc[4][4] = {};
  int am = tid >> 2, aq = tid & 3;     // A loader: row am (0..63), quad aq (0..3)
  int bk = tid >> 4, bq = tid & 15;    // B loader: k-row bk (0..15), quad bq (0..15)
  const float* Ap = A + (size_t)(mBase + am) * K + aq*4;
  for (int k0 = 0; k0 < K; k0 += 16){
    float4 av = *(const float4*)(Ap + k0);
    float4 bv;
    int gn = nBase + bq*4;
    const float* Wp = W + (size_t)(k0 + bk) * N + gn;
    if (gn + 3 < N) bv = *(const float4*)Wp;
    else {
      bv.x = (gn+0<N)?Wp[0]:0.f; bv.y = (gn+1<N)?Wp[1]:0.f;
      bv.z = (gn+2<N)?Wp[2]:0.f; bv.w = (gn+3<N)?Wp[3]:0.f;
    }
    __syncthreads();
    As[aq*4+0][am]=av.x; As[aq*4+1][am]=av.y; As[aq*4+2][am]=av.z; As[aq*4+3][am]=av.w;
    *(float4*)&Bs[bk][bq*4] = bv;
    __syncthreads();
    #pragma unroll
    for (int kk=0;kk<16;kk++){
      float a_[4], b_[4];
      #pragma unroll
      for (int u=0;u<4;u++){ a_[u]=As[kk][ty*4+u]; b_[u]=Bs[kk][tx*4+u]; }
      #pragma unroll
      for (int u=0;u<4;u++)
        #pragma unroll
        for (int v2=0;v2<4;v2++) acc[u][v2] += a_[u]*b_[v2];
    }
  }
  #pragma unroll
  for (int u=0;u<4;u++){
    int gm = mBase + ty*4 + u;
    float* Cp = C + (size_t)gm*N + nBase + tx*4;
    #pragma unroll
    for (int v2=0;v2<4;v2++){
      int gn = nBase + tx*4 + v2;
      if (gn < N){
        float o = acc[u][v2];
        if (ACCUM) o += Cp[v2];
        Cp[v2] = o;
      }
    }
  }
}

// ---------------- dt = softplus(raw + bias); dA = dt*(-exp(Alog)); per-chunk cumsum
__global__ __launch_bounds__(256) void dt_scan(const float* __restrict__ zx,
    const float* __restrict__ dtb, const float* __restrict__ alog,
    float* __restrict__ dtt, float* __restrict__ acs){
  int b = blockIdx.x / NH, h = blockIdx.x % NH;
  int tid = threadIdx.x;
  float negA = -expf(alog[h]);
  float bias = dtb[h];
  __shared__ float sc[256];
  for (int c=0;c<NCH;c++){
    int l = c*CHUNKC + tid;
    float xv = zx[((size_t)(b*SEQ+l))*PDIM + (DI+CDIM) + h] + bias;
    float dt = softplusf_(xv);
    float v = dt*negA;
    sc[tid]=v; __syncthreads();
    #pragma unroll
    for (int off=1; off<256; off<<=1){
      float t = (tid>=off)? sc[tid-off]:0.f;
      __syncthreads();
      v += t; sc[tid]=v;
      __syncthreads();
    }
    dtt[(b*NH+h)*SEQ + l] = dt;
    acs[(b*NH+h)*SEQ + l] = v;
  }
}

// ---------------- depthwise causal conv (K=4) + SiLU -> xbc (b,l,c) ------------
__global__ __launch_bounds__(256) void dwconv(const float* __restrict__ zx,
    const float* __restrict__ w, const float* __restrict__ bias,
    float* __restrict__ out){
  int idx = blockIdx.x*256+threadIdx.x;
  if (idx >= BATCH*SEQ*CDIM) return;
  int c = idx % CDIM;
  int l = (idx/CDIM) % SEQ;
  int b = idx / (CDIM*SEQ);
  float s = bias[c];
  const float* col = zx + (size_t)(b*SEQ)*PDIM + DI + c;
  #pragma unroll
  for (int k=0;k<4;k++){
    int li = l-3+k;
    if (li>=0) s += w[c*4+k]*col[(size_t)li*PDIM];
  }
  out[idx] = siluf_(s);
}

// ---------------- SSD: per-chunk states[b,c,h,p,n] = sum_j B[j,n]*dec_j*Xd[j,p]
__global__ __launch_bounds__(256) void ssd_states(const float* __restrict__ xbc,
    const float* __restrict__ dtt, const float* __restrict__ acs,
    float* __restrict__ states){
  int blk = blockIdx.x;
  int h = blk % NH, c = (blk/NH) % NCH, b = blk/(NH*NCH);
  int tid = threadIdx.x;
  __shared__ float bs[32][DSTATE];
  __shared__ float xs[32][HD];
  __shared__ float dec[32];
  float acs_last = acs[(b*NH+h)*SEQ + c*CHUNKC + CHUNKC-1];
  int p = tid & 63, ng = tid >> 6;
  float accv[32];
  #pragma unroll
  for (int nn=0;nn<32;nn++) accv[nn]=0.f;
  for (int jt=0; jt<CHUNKC/32; jt++){
    __syncthreads();
    for (int t=tid; t<32*32; t+=256){
      int jj = t >> 5, q = t & 31;
      int lj = c*CHUNKC + jt*32 + jj;
      ((float4*)&bs[jj][0])[q] = *(const float4*)(xbc + ((size_t)(b*SEQ+lj))*CDIM + DI + q*4);
    }
    for (int t=tid; t<32*16; t+=256){
      int jj = t >> 4, q = t & 15;
      int lj = c*CHUNKC + jt*32 + jj;
      float d = dtt[(b*NH+h)*SEQ + lj];
      float4 v = *(const float4*)(xbc + ((size_t)(b*SEQ+lj))*CDIM + h*HD + q*4);
      v.x*=d; v.y*=d; v.z*=d; v.w*=d;
      ((float4*)&xs[jj][0])[q] = v;
    }
    if (tid < 32){
      int lj = c*CHUNKC + jt*32 + tid;
      dec[tid] = expf(acs_last - acs[(b*NH+h)*SEQ + lj]);
    }
    __syncthreads();
    for (int jj=0;jj<32;jj++){
      float f = dec[jj]*xs[jj][p];
      const float* br = &bs[jj][ng*32];
      #pragma unroll
      for (int nn=0;nn<32;nn++) accv[nn] += f*br[nn];
    }
  }
  float* sp = states + (((size_t)(b*NCH+c)*NH + h) << 13) + p*DSTATE + ng*32;
  #pragma unroll
  for (int nn=0;nn<32;nn++) sp[nn] = accv[nn];
}

// ---------------- inter-chunk scan: prev[c] = carry; carry = carry*dec_c + st_c
__global__ __launch_bounds__(256) void ssd_scan(const float* __restrict__ states,
    const float* __restrict__ acs, float* __restrict__ prev){
  int idx = blockIdx.x*256+threadIdx.x;
  if (idx >= BATCH*NH*HD*DSTATE) return;
  int pn = idx & 8191;
  int bh = idx >> 13;
  int h = bh % NH, b = bh / NH;
  float carry = 0.f;
  #pragma unroll
  for (int c=0;c<NCH;c++){
    size_t o = (((size_t)(b*NCH+c)*NH + h) << 13) + pn;
    prev[o] = carry;
    float dec = expf(acs[(b*NH+h)*SEQ + c*CHUNKC + CHUNKC-1]);
    carry = carry*dec + states[o];
  }
}

// ---------------- SSD diag + off-diag + skip -> Y (b,l,h,p) --------------------
__global__ __launch_bounds__(256,1) void ssd_diag(const float* __restrict__ xbc,
    const float* __restrict__ dtt, const float* __restrict__ acs,
    const float* __restrict__ prev, const float* __restrict__ dskip,
    float* __restrict__ Y){
  int blk = blockIdx.x;
  int h = blk % NH, c = (blk/NH) % NCH, b = blk/(NH*NCH);
  int i = threadIdx.x;
  int li = c*CHUNKC + i;
  __shared__ float bs[32][DSTATE];   // 16 KB
  __shared__ float xs[32][HD];       //  8 KB
  __shared__ float pv[HD][DSTATE];   // 32 KB
  __shared__ float ac[CHUNKC];       //  1 KB
  float myacs = acs[(b*NH+h)*SEQ + li];
  ac[i] = myacs;
  {
    const float4* src = (const float4*)(prev + (((size_t)(b*NCH+c)*NH + h) << 13));
    float4* dst = (float4*)&pv[0][0];
    for (int t=i; t<HD*DSTATE/4; t+=256) dst[t]=src[t];
  }
  float creg[DSTATE];
  {
    const float4* cp = (const float4*)(xbc + ((size_t)(b*SEQ+li))*CDIM + DI + DSTATE);
    #pragma unroll
    for (int q=0;q<DSTATE/4;q++){
      float4 v = cp[q];
      creg[4*q]=v.x; creg[4*q+1]=v.y; creg[4*q+2]=v.z; creg[4*q+3]=v.w;
    }
  }
  float y[HD];
  #pragma unroll
  for (int p=0;p<HD;p++) y[p]=0.f;

  for (int jt=0; jt<CHUNKC/32; jt++){
    __syncthreads();
    for (int t=i; t<32*32; t+=256){
      int jj = t >> 5, q = t & 31;
      int lj = c*CHUNKC + jt*32 + jj;
      ((float4*)&bs[jj][0])[q] = *(const float4*)(xbc + ((size_t)(b*SEQ+lj))*CDIM + DI + q*4);
    }
    for (int t=i; t<32*16; t+=256){
      int jj = t >> 4, q = t & 15;
      int lj = c*CHUNKC + jt*32 + jj;
      float d = dtt[(b*NH+h)*SEQ + lj];
      float4 v = *(const float4*)(xbc + ((size_t)(b*SEQ+lj))*CDIM + h*HD + q*4);
      v.x*=d; v.y*=d; v.z*=d; v.w*=d;
      ((float4*)&xs[jj][0])[q] = v;
    }
    __syncthreads();
    int jmax = i - jt*32 + 1;
    if (jmax > 32) jmax = 32;
    for (int jj=0; jj<jmax; jj++){
      float s = 0.f;
      #pragma unroll
      for (int n=0;n<DSTATE;n++) s += creg[n]*bs[jj][n];
      float wgt = expf(myacs - ac[jt*32+jj]) * s;
      const float* xr = &xs[jj][0];
      #pragma unroll
      for (int p=0;p<HD;p++) y[p] += wgt*xr[p];
    }
  }
  float e = expf(myacs);
  #pragma unroll
  for (int p=0;p<HD;p++){
    float s=0.f;
    #pragma unroll
    for (int n=0;n<DSTATE;n++) s += creg[n]*pv[p][n];
    y[p] += e*s;
  }
  float dsk = dskip[h];
  const float* xh = xbc + ((size_t)(b*SEQ+li))*CDIM + h*HD;
  float* yp = Y + ((size_t)(b*SEQ+li))*DI + h*HD;
  #pragma unroll
  for (int p=0;p<HD;p++) yp[p] = y[p] + dsk*xh[p];
}

// ---------------- gate (silu(z)) + rmsnorm over 1536, in-place on Y ------------
__global__ __launch_bounds__(256) void gate_rms(const float* __restrict__ zx,
    const float* __restrict__ gnw, float* __restrict__ Y){
  int row = blockIdx.x;
  const float* z = zx + (size_t)row*PDIM;
  float* y = Y + (size_t)row*DI;
  float vals[6]; float ss=0.f;
  #pragma unroll
  for (int t=0;t<6;t++){
    int d = threadIdx.x + t*256;
    float v = y[d]*siluf_(z[d]);
    vals[t]=v; ss+=v*v;
  }
  __shared__ float red[4];
  float tot = block_sum_256(ss, red);
  float sc = rsqrtf(tot*(1.f/DI)+EPSF);
  #pragma unroll
  for (int t=0;t<6;t++){
    int d = threadIdx.x + t*256;
    y[d] = vals[t]*sc*gnw[d];
  }
}

// ---------------- final pooling + head -----------------------------------------
__global__ __launch_bounds__(256) void mean_pool(const float* __restrict__ hn,
    float* __restrict__ pooled){
  int idx = blockIdx.x*256+threadIdx.x;
  if (idx >= BATCH*DM) return;
  int b = idx / DM, d = idx % DM;
  float s = 0.f;
  for (int l=0;l<SEQ;l++) s += hn[((size_t)(b*SEQ+l))*DM + d];
  pooled[idx] = s * (1.f/SEQ);
}

__global__ __launch_bounds__(512) void head_k(const float* __restrict__ pooled,
    const float* __restrict__ w1, const float* __restrict__ b1,
    const float* __restrict__ g, const float* __restrict__ bb,
    const float* __restrict__ mn, const float* __restrict__ vr,
    const float* __restrict__ w2, const float* __restrict__ b2,
    float* __restrict__ out){
  int b = blockIdx.x;
  int j = threadIdx.x;
  __shared__ float f[512];
  __shared__ float pl[DM];
  for (int t=j; t<DM; t+=512) pl[t] = pooled[b*DM+t];
  __syncthreads();
  float s = b1[j];
  for (int k=0;k<DM;k++) s += pl[k]*w1[k*512+j];
  s = (s-mn[j])*(g[j]*rsqrtf(vr[j]+EPSF)) + bb[j];
  f[j] = fmaxf(s,0.f);
  __syncthreads();
  if (j < 27){
    float o = b2[j];
    for (int k=0;k<512;k++) o += f[k]*w2[k*27+j];
    out[b*27+j] = o;
  }
}

extern "C" void kernel_launch(void* const* d_in, const int* in_sizes, int n_in,
                              void* d_out, int out_size, void* d_ws, size_t ws_size,
                              hipStream_t stream){
  const float* x      = (const float*)d_in[0];
  const float* c1_w   = (const float*)d_in[1];
  const float* c1_b   = (const float*)d_in[2];
  const float* bn1_g  = (const float*)d_in[3];
  const float* bn1_b  = (const float*)d_in[4];
  const float* bn1_m  = (const float*)d_in[5];
  const float* bn1_v  = (const float*)d_in[6];
  const float* c2_w   = (const float*)d_in[7];
  const float* c2_b   = (const float*)d_in[8];
  const float* bn2_g  = (const float*)d_in[9];
  const float* bn2_b  = (const float*)d_in[10];
  const float* bn2_m  = (const float*)d_in[11];
  const float* bn2_v  = (const float*)d_in[12];
  const float* c3_w   = (const float*)d_in[13];
  const float* c3_b   = (const float*)d_in[14];
  const float* bn3_g  = (const float*)d_in[15];
  const float* bn3_b  = (const float*)d_in[16];
  const float* bn3_m  = (const float*)d_in[17];
  const float* bn3_v  = (const float*)d_in[18];
  const float* ln_w   = (const float*)d_in[19];
  const float* inpw   = (const float*)d_in[20];
  const float* convw  = (const float*)d_in[21];
  const float* convb  = (const float*)d_in[22];
  const float* dtb    = (const float*)d_in[23];
  const float* alog   = (const float*)d_in[24];
  const float* dskip  = (const float*)d_in[25];
  const float* gnw    = (const float*)d_in[26];
  const float* outw   = (const float*)d_in[27];
  const float* normfw = (const float*)d_in[28];
  const float* fc1w   = (const float*)d_in[29];
  const float* fc1b   = (const float*)d_in[30];
  const float* bncg   = (const float*)d_in[31];
  const float* bncb   = (const float*)d_in[32];
  const float* bncm   = (const float*)d_in[33];
  const float* bncv   = (const float*)d_in[34];
  const float* fc2w   = (const float*)d_in[35];
  const float* fc2b   = (const float*)d_in[36];
  (void)in_sizes; (void)n_in; (void)out_size; (void)ws_size;

  float* ws = (float*)d_ws;
  size_t off = 0;
  auto alloc = [&](size_t n){ float* p = ws + off; off += n; return p; };
  float* h1  = alloc((size_t)BATCH*192*LS1);         // stem1 out
  float* h2  = alloc((size_t)BATCH*384*LS2);         // stem2 out
  float* h   = alloc((size_t)BATCH*SEQ*DM);          // residual stream
  float* hn  = alloc((size_t)BATCH*SEQ*DM);          // rmsnorm buffer
  float* zx  = alloc((size_t)BATCH*SEQ*PDIM);        // in_proj out
  float* xbc = alloc((size_t)BATCH*SEQ*CDIM);        // dwconv out
  float* dtt = alloc((size_t)BATCH*NH*SEQ);          // dt  (b,h,l)
  float* acs = alloc((size_t)BATCH*NH*SEQ);          // per-chunk cumsum of dA (b,h,l)
  float* st  = alloc((size_t)BATCH*NCH*NH*HD*DSTATE);// chunk states
  float* pv  = alloc((size_t)BATCH*NCH*NH*HD*DSTATE);// prev states
  float* Y   = alloc((size_t)BATCH*SEQ*DI);          // ssd out / gated
  float* pooled = alloc((size_t)BATCH*DM);

  // ---- stem ----
  conv_stem1<<<(BATCH*192*LS1+255)/256,256,0,stream>>>(x, c1_w,c1_b, bn1_g,bn1_b,bn1_m,bn1_v, h1);
  conv_stem2<<<(BATCH*384*LS2+255)/256,256,0,stream>>>(h1, c2_w,c2_b, bn2_g,bn2_b,bn2_m,bn2_v, h2);
  conv_stem3<<<(BATCH*LS2*768+255)/256,256,0,stream>>>(h2, c3_w,c3_b, bn3_g,bn3_b,bn3_m,bn3_v, h);

  // ---- layers ----
  const int M = BATCH*SEQ;  // 2048
  for (int l=0; l<NLAYER; l++){
    rmsnorm768<<<M,256,0,stream>>>(h, ln_w + (size_t)l*DM, hn);
    gemm_f32<0><<<dim3((PDIM+63)/64, M/64),256,0,stream>>>(hn, inpw + (size_t)l*DM*PDIM, zx, M, PDIM, DM);
    dt_scan<<<BATCH*NH,256,0,stream>>>(zx, dtb + l*NH, alog + l*NH, dtt, acs);
    dwconv<<<(BATCH*SEQ*CDIM+255)/256,256,0,stream>>>(zx, convw + (size_t)l*CDIM*4, convb + (size_t)l*CDIM, xbc);
    ssd_states<<<BATCH*NCH*NH,256,0,stream>>>(xbc, dtt, acs, st);
    ssd_scan<<<(BATCH*NH*HD*DSTATE+255)/256,256,0,stream>>>(st, acs, pv);
    ssd_diag<<<BATCH*NCH*NH,256,0,stream>>>(xbc, dtt, acs, pv, dskip + l*NH, Y);
    gate_rms<<<M,256,0,stream>>>(zx, gnw + (size_t)l*DI, Y);
    gemm_f32<1><<<dim3(DM/64, M/64),256,0,stream>>>(Y, outw + (size_t)l*DI*DM, h, M, DM, DI);
  }

  // ---- head ----
  rmsnorm768<<<M,256,0,stream>>>(h, normfw, hn);
  mean_pool<<<(BATCH*DM+255)/256,256,0,stream>>>(hn, pooled);
  head_k<<<BATCH,512,0,stream>>>(pooled, fc1w, fc1b, bncg,bncb,bncm,bncv, fc2w, fc2b, (float*)d_out);
}

// Round 2
// 23847.318 us; speedup vs baseline: 1.1640x; 1.1640x over previous
//
#include <hip/hip_runtime.h>
#include <math.h>

#define DEV __device__ __forceinline__

constexpr int BATCH = 2;
constexpr int L0 = 4096;
constexpr int LS1 = 2048;
constexpr int LS2 = 1024;
constexpr int SEQ = 1024;
constexpr int DM = 768;
constexpr int NH = 24;
constexpr int HD = 64;
constexpr int DI = 1536;
constexpr int DSTATE = 128;
constexpr int CDIM = 1792;   // DI + 2*DSTATE
constexpr int PDIM = 3352;   // 2*DI + 2*DSTATE + NH
constexpr int PPAD = 3456;   // PDIM padded to 27*128
constexpr int CHUNKC = 256;
constexpr int NCH = 4;
constexpr int NLAYER = 24;
constexpr float EPSF = 1e-5f;

typedef short bf16x8 __attribute__((ext_vector_type(8)));
typedef float f32x4 __attribute__((ext_vector_type(4)));

DEV float sigmoidf_(float x){ return 1.f/(1.f+expf(-x)); }
DEV float siluf_(float x){ return x*sigmoidf_(x); }
DEV float geluf_(float x){ return 0.5f*x*(1.f+erff(x*0.70710678118654752440f)); }
DEV float softplusf_(float x){ return fmaxf(x,0.f) + log1pf(expf(-fabsf(x))); }

DEV unsigned short f2bf(float x){
  union { float f; unsigned int u; } v; v.f = x;
  unsigned int u = v.u;
  unsigned int r = (u + 0x7fffu + ((u>>16)&1u)) >> 16;
  return (unsigned short)r;
}

DEV void load_lds16(const void* g, void* l){
  __builtin_amdgcn_global_load_lds(
      (const __attribute__((address_space(1))) unsigned int*)g,
      (__attribute__((address_space(3))) unsigned int*)l,
      16, 0, 0);
}

DEV float block_sum_256(float v, float* red4){
  #pragma unroll
  for (int o=32;o>0;o>>=1) v += __shfl_down(v,o,64);
  int tid = threadIdx.x;
  __syncthreads();
  if ((tid&63)==0) red4[tid>>6]=v;
  __syncthreads();
  return red4[0]+red4[1]+red4[2]+red4[3];
}

// ---------------- stem ----------------
__global__ __launch_bounds__(256) void conv_stem1(const float* __restrict__ x,
    const float* __restrict__ w, const float* __restrict__ bias,
    const float* __restrict__ g, const float* __restrict__ bb,
    const float* __restrict__ mn, const float* __restrict__ vr,
    float* __restrict__ out){
  int idx = blockIdx.x*256+threadIdx.x;
  if (idx >= BATCH*192*LS1) return;
  int lo = idx & (LS1-1);
  int co = (idx >> 11) % 192;
  int b  = idx / (192*LS1);
  float s = bias[co];
  const float* wr = w + co*60;
  #pragma unroll
  for (int ci=0; ci<12; ci++){
    const float* xr = x + ((size_t)(b*12+ci))*L0;
    #pragma unroll
    for (int k=0;k<5;k++){
      int li = lo*2 + k - 2;
      if (li>=0 && li<L0) s += wr[ci*5+k]*xr[li];
    }
  }
  s = geluf_(s);
  s = (s-mn[co])*(g[co]*rsqrtf(vr[co]+EPSF)) + bb[co];
  out[idx] = s;
}

__global__ __launch_bounds__(256) void conv_stem2(const float* __restrict__ x,
    const float* __restrict__ w, const float* __restrict__ bias,
    const float* __restrict__ g, const float* __restrict__ bb,
    const float* __restrict__ mn, const float* __restrict__ vr,
    float* __restrict__ out){
  int idx = blockIdx.x*256+threadIdx.x;
  if (idx >= BATCH*384*LS2) return;
  int lo = idx & (LS2-1);
  int co = (idx >> 10) % 384;
  int b  = idx / (384*LS2);
  float s = bias[co];
  const float* wr = w + co*(192*3);
  const float* xb = x + (size_t)b*192*LS1;
  for (int ci=0; ci<192; ci++){
    const float* base = xb + ci*LS1;
    int l2 = lo*2;
    s += wr[ci*3+1]*base[l2];
    s += wr[ci*3+2]*base[l2+1];
    if (lo>0) s += wr[ci*3]*base[l2-1];
  }
  s = geluf_(s);
  s = (s-mn[co])*(g[co]*rsqrtf(vr[co]+EPSF)) + bb[co];
  out[idx] = s;
}

__global__ __launch_bounds__(256) void conv_stem3(const float* __restrict__ x,
    const float* __restrict__ w, const float* __restrict__ bias,
    const float* __restrict__ g, const float* __restrict__ bb,
    const float* __restrict__ mn, const float* __restrict__ vr,
    float* __restrict__ h){
  int idx = blockIdx.x*256+threadIdx.x;
  if (idx >= BATCH*LS2*768) return;
  int co = idx % 768;
  int lo = (idx/768) % LS2;
  int b  = idx / (768*LS2);
  float s = bias[co];
  const float* wr = w + (size_t)co*384*3;
  const float* xb = x + (size_t)b*384*LS2;
  for (int ci=0; ci<384; ci++){
    const float* xr = xb + ci*LS2 + lo;
    s += wr[ci*3+1]*xr[0];
    if (lo>0)     s += wr[ci*3]*xr[-1];
    if (lo<LS2-1) s += wr[ci*3+2]*xr[1];
  }
  s = geluf_(s);
  s = (s-mn[co])*(g[co]*rsqrtf(vr[co]+EPSF)) + bb[co];
  h[((size_t)(b*SEQ+lo))*DM + co] = s;
}

// ---------------- rmsnorm (D=768), optional bf16 output ----------------
template<int BF>
__global__ __launch_bounds__(256) void rmsnorm768(const float* __restrict__ in,
    const float* __restrict__ w, float* __restrict__ outf, unsigned short* __restrict__ outb){
  int row = blockIdx.x;
  const float* p = in + (size_t)row*DM;
  float v0[3]; float ss=0.f;
  #pragma unroll
  for (int t=0;t<3;t++){ float q = p[threadIdx.x + t*256]; v0[t]=q; ss+=q*q; }
  __shared__ float red[4];
  float tot = block_sum_256(ss, red);
  float sc = rsqrtf(tot*(1.f/DM) + EPSF);
  #pragma unroll
  for (int t=0;t<3;t++){
    int d = threadIdx.x + t*256;
    float o = v0[t]*sc*w[d];
    if (BF) outb[(size_t)row*DM + d] = f2bf(o);
    else    outf[(size_t)row*DM + d] = o;
  }
}

// ---------------- transpose + fp32->bf16 convert: in (R,Cin) -> out (Cpad,R) ---
__global__ __launch_bounds__(256) void transpose_cvt(const float* __restrict__ in,
    unsigned short* __restrict__ out, int R, int Cin, int Cpad){
  __shared__ float t[32][33];
  int c0 = blockIdx.x*32, r0 = blockIdx.y*32;
  int tx = threadIdx.x & 31, ty = threadIdx.x >> 5;   // 32 x 8
  #pragma unroll
  for (int i=0;i<32;i+=8){
    int r = r0+ty+i, c = c0+tx;
    t[ty+i][tx] = (c<Cin) ? in[(size_t)r*Cin + c] : 0.f;
  }
  __syncthreads();
  #pragma unroll
  for (int i=0;i<32;i+=8){
    int c = c0+ty+i, r = r0+tx;
    if (c < Cpad) out[(size_t)c*R + r] = f2bf(t[tx][ty+i]);
  }
}

// ---------------- bf16 MFMA GEMM: C[M,Ntrue] (+)= A[M,K] @ Bt[N,K]^T -----------
// 128x128 tile, BK=32, 4 waves, 16x16x32 bf16 MFMA, global_load_lds staging.
// M%128==0, K%32==0, grid.x*128 = Npad (Bt has Npad rows).
template<int ACCUM>
__global__ __launch_bounds__(256,2) void gemm_bf16(const unsigned short* __restrict__ A,
    const unsigned short* __restrict__ Bt, float* __restrict__ C,
    int Ntrue, int K, int ldc){
  __shared__ alignas(16) unsigned short As[128*32];
  __shared__ alignas(16) unsigned short Bs[128*32];
  int tid = threadIdx.x;
  int wave = tid >> 6, lane = tid & 63;
  int mBase = blockIdx.y*128, nBase = blockIdx.x*128;
  const size_t K2 = (size_t)K*2;
  int o0 = wave*1024 + lane*16;          // byte offset in 4KB-chunk staging map
  int o1 = o0 + 4096;
  const char* Ag0 = (const char*)A + (size_t)(mBase + (o0>>6))*K2 + (o0&63);
  const char* Ag1 = (const char*)A + (size_t)(mBase + (o1>>6))*K2 + (o1&63);
  const char* Bg0 = (const char*)Bt + (size_t)(nBase + (o0>>6))*K2 + (o0&63);
  const char* Bg1 = (const char*)Bt + (size_t)(nBase + (o1>>6))*K2 + (o1&63);
  char* AsW = (char*)As + wave*1024;
  char* BsW = (char*)Bs + wave*1024;

  int wm = (wave>>1)*64, wn = (wave&1)*64;
  int ln = lane & 15, quad = lane >> 4;

  f32x4 acc[4][4];
  #pragma unroll
  for (int i=0;i<4;i++)
    #pragma unroll
    for (int j=0;j<4;j++) acc[i][j] = (f32x4){0.f,0.f,0.f,0.f};

  for (int k0=0; k0<K; k0+=32){
    size_t kb = (size_t)k0*2;
    __syncthreads();
    load_lds16(Ag0 + kb, AsW);
    load_lds16(Ag1 + kb, AsW + 4096);
    load_lds16(Bg0 + kb, BsW);
    load_lds16(Bg1 + kb, BsW + 4096);
    __syncthreads();
    bf16x8 a[4], b[4];
    #pragma unroll
    for (int mt=0;mt<4;mt++)
      a[mt] = *(const bf16x8*)((const char*)As + (size_t)(wm+mt*16+ln)*64 + quad*16);
    #pragma unroll
    for (int nt=0;nt<4;nt++)
      b[nt] = *(const bf16x8*)((const char*)Bs + (size_t)(wn+nt*16+ln)*64 + quad*16);
    #pragma unroll
    for (int mt=0;mt<4;mt++)
      #pragma unroll
      for (int nt=0;nt<4;nt++)
        acc[mt][nt] = __builtin_amdgcn_mfma_f32_16x16x32_bf16(a[mt], b[nt], acc[mt][nt], 0,0,0);
  }

  #pragma unroll
  for (int mt=0;mt<4;mt++){
    #pragma unroll
    for (int nt=0;nt<4;nt++){
      int col = nBase + wn + nt*16 + ln;
      int row0 = mBase + wm + mt*16 + quad*4;
      if (col < Ntrue){
        #pragma unroll
        for (int r=0;r<4;r++){
          float* p = C + (size_t)(row0+r)*ldc + col;
          float v = acc[mt][nt][r];
          if (ACCUM) v += *p;
          *p = v;
        }
      }
    }
  }
}

// ---------------- dt cumsum ----------------
__global__ __launch_bounds__(256) void dt_scan(const float* __restrict__ zx,
    const float* __restrict__ dtb, const float* __restrict__ alog,
    float* __restrict__ dtt, float* __restrict__ acs){
  int b = blockIdx.x / NH, h = blockIdx.x % NH;
  int tid = threadIdx.x;
  float negA = -expf(alog[h]);
  float bias = dtb[h];
  __shared__ float sc[256];
  for (int c=0;c<NCH;c++){
    int l = c*CHUNKC + tid;
    float xv = zx[((size_t)(b*SEQ+l))*PDIM + (DI+CDIM) + h] + bias;
    float dt = softplusf_(xv);
    float v = dt*negA;
    sc[tid]=v; __syncthreads();
    #pragma unroll
    for (int off=1; off<256; off<<=1){
      float t = (tid>=off)? sc[tid-off]:0.f;
      __syncthreads();
      v += t; sc[tid]=v;
      __syncthreads();
    }
    dtt[(b*NH+h)*SEQ + l] = dt;
    acs[(b*NH+h)*SEQ + l] = v;
  }
}

// ---------------- depthwise causal conv (K=4) + SiLU ------------
__global__ __launch_bounds__(256) void dwconv(const float* __restrict__ zx,
    const float* __restrict__ w, const float* __restrict__ bias,
    float* __restrict__ out){
  int idx = blockIdx.x*256+threadIdx.x;
  if (idx >= BATCH*SEQ*CDIM) return;
  int c = idx % CDIM;
  int l = (idx/CDIM) % SEQ;
  int b = idx / (CDIM*SEQ);
  float s = bias[c];
  const float* col = zx + (size_t)(b*SEQ)*PDIM + DI + c;
  #pragma unroll
  for (int k=0;k<4;k++){
    int li = l-3+k;
    if (li>=0) s += w[c*4+k]*col[(size_t)li*PDIM];
  }
  out[idx] = siluf_(s);
}

// ---------------- SSD: chunk states ----------------
__global__ __launch_bounds__(256) void ssd_states(const float* __restrict__ xbc,
    const float* __restrict__ dtt, const float* __restrict__ acs,
    float* __restrict__ states){
  int blk = blockIdx.x;
  int h = blk % NH, c = (blk/NH) % NCH, b = blk/(NH*NCH);
  int tid = threadIdx.x;
  __shared__ float bs[32][DSTATE];
  __shared__ float xs[32][HD];
  __shared__ float dec[32];
  float acs_last = acs[(b*NH+h)*SEQ + c*CHUNKC + CHUNKC-1];
  int p = tid & 63, ng = tid >> 6;
  float accv[32];
  #pragma unroll
  for (int nn=0;nn<32;nn++) accv[nn]=0.f;
  for (int jt=0; jt<CHUNKC/32; jt++){
    __syncthreads();
    for (int t=tid; t<32*32; t+=256){
      int jj = t >> 5, q = t & 31;
      int lj = c*CHUNKC + jt*32 + jj;
      ((float4*)&bs[jj][0])[q] = *(const float4*)(xbc + ((size_t)(b*SEQ+lj))*CDIM + DI + q*4);
    }
    for (int t=tid; t<32*16; t+=256){
      int jj = t >> 4, q = t & 15;
      int lj = c*CHUNKC + jt*32 + jj;
      float d = dtt[(b*NH+h)*SEQ + lj];
      float4 v = *(const float4*)(xbc + ((size_t)(b*SEQ+lj))*CDIM + h*HD + q*4);
      v.x*=d; v.y*=d; v.z*=d; v.w*=d;
      ((float4*)&xs[jj][0])[q] = v;
    }
    if (tid < 32){
      int lj = c*CHUNKC + jt*32 + tid;
      dec[tid] = expf(acs_last - acs[(b*NH+h)*SEQ + lj]);
    }
    __syncthreads();
    for (int jj=0;jj<32;jj++){
      float f = dec[jj]*xs[jj][p];
      const float* br = &bs[jj][ng*32];
      #pragma unroll
      for (int nn=0;nn<32;nn++) accv[nn] += f*br[nn];
    }
  }
  float* sp = states + (((size_t)(b*NCH+c)*NH + h) << 13) + p*DSTATE + ng*32;
  #pragma unroll
  for (int nn=0;nn<32;nn++) sp[nn] = accv[nn];
}

// ---------------- inter-chunk scan ----------------
__global__ __launch_bounds__(256) void ssd_scan(const float* __restrict__ states,
    const float* __restrict__ acs, float* __restrict__ prev){
  int idx = blockIdx.x*256+threadIdx.x;
  if (idx >= BATCH*NH*HD*DSTATE) return;
  int pn = idx & 8191;
  int bh = idx >> 13;
  int h = bh % NH, b = bh / NH;
  float carry = 0.f;
  #pragma unroll
  for (int c=0;c<NCH;c++){
    size_t o = (((size_t)(b*NCH+c)*NH + h) << 13) + pn;
    prev[o] = carry;
    float dec = expf(acs[(b*NH+h)*SEQ + c*CHUNKC + CHUNKC-1]);
    carry = carry*dec + states[o];
  }
}

// ---------------- SSD diag + off-diag + skip ----------------
__global__ __launch_bounds__(256,1) void ssd_diag(const float* __restrict__ xbc,
    const float* __restrict__ dtt, const float* __restrict__ acs,
    const float* __restrict__ prev, const float* __restrict__ dskip,
    float* __restrict__ Y){
  int blk = blockIdx.x;
  int h = blk % NH, c = (blk/NH) % NCH, b = blk/(NH*NCH);
  int i = threadIdx.x;
  int li = c*CHUNKC + i;
  __shared__ float bs[32][DSTATE];
  __shared__ float xs[32][HD];
  __shared__ float pv[HD][DSTATE];
  __shared__ float ac[CHUNKC];
  float myacs = acs[(b*NH+h)*SEQ + li];
  ac[i] = myacs;
  {
    const float4* src = (const float4*)(prev + (((size_t)(b*NCH+c)*NH + h) << 13));
    float4* dst = (float4*)&pv[0][0];
    for (int t=i; t<HD*DSTATE/4; t+=256) dst[t]=src[t];
  }
  float creg[DSTATE];
  {
    const float4* cp = (const float4*)(xbc + ((size_t)(b*SEQ+li))*CDIM + DI + DSTATE);
    #pragma unroll
    for (int q=0;q<DSTATE/4;q++){
      float4 v = cp[q];
      creg[4*q]=v.x; creg[4*q+1]=v.y; creg[4*q+2]=v.z; creg[4*q+3]=v.w;
    }
  }
  float y[HD];
  #pragma unroll
  for (int p=0;p<HD;p++) y[p]=0.f;

  for (int jt=0; jt<CHUNKC/32; jt++){
    __syncthreads();
    for (int t=i; t<32*32; t+=256){
      int jj = t >> 5, q = t & 31;
      int lj = c*CHUNKC + jt*32 + jj;
      ((float4*)&bs[jj][0])[q] = *(const float4*)(xbc + ((size_t)(b*SEQ+lj))*CDIM + DI + q*4);
    }
    for (int t=i; t<32*16; t+=256){
      int jj = t >> 4, q = t & 15;
      int lj = c*CHUNKC + jt*32 + jj;
      float d = dtt[(b*NH+h)*SEQ + lj];
      float4 v = *(const float4*)(xbc + ((size_t)(b*SEQ+lj))*CDIM + h*HD + q*4);
      v.x*=d; v.y*=d; v.z*=d; v.w*=d;
      ((float4*)&xs[jj][0])[q] = v;
    }
    __syncthreads();
    int jmax = i - jt*32 + 1;
    if (jmax > 32) jmax = 32;
    for (int jj=0; jj<jmax; jj++){
      float s = 0.f;
      #pragma unroll
      for (int n=0;n<DSTATE;n++) s += creg[n]*bs[jj][n];
      float wgt = expf(myacs - ac[jt*32+jj]) * s;
      const float* xr = &xs[jj][0];
      #pragma unroll
      for (int p=0;p<HD;p++) y[p] += wgt*xr[p];
    }
  }
  float e = expf(myacs);
  #pragma unroll
  for (int p=0;p<HD;p++){
    float s=0.f;
    #pragma unroll
    for (int n=0;n<DSTATE;n++) s += creg[n]*pv[p][n];
    y[p] += e*s;
  }
  float dsk = dskip[h];
  const float* xh = xbc + ((size_t)(b*SEQ+li))*CDIM + h*HD;
  float* yp = Y + ((size_t)(b*SEQ+li))*DI + h*HD;
  #pragma unroll
  for (int p=0;p<HD;p++) yp[p] = y[p] + dsk*xh[p];
}

// ---------------- gate (silu(z)) + rmsnorm over 1536 -> bf16 ------------
__global__ __launch_bounds__(256) void gate_rms(const float* __restrict__ zx,
    const float* __restrict__ gnw, const float* __restrict__ Y,
    unsigned short* __restrict__ Yb){
  int row = blockIdx.x;
  const float* z = zx + (size_t)row*PDIM;
  const float* y = Y + (size_t)row*DI;
  float vals[6]; float ss=0.f;
  #pragma unroll
  for (int t=0;t<6;t++){
    int d = threadIdx.x + t*256;
    float v = y[d]*siluf_(z[d]);
    vals[t]=v; ss+=v*v;
  }
  __shared__ float red[4];
  float tot = block_sum_256(ss, red);
  float sc = rsqrtf(tot*(1.f/DI)+EPSF);
  #pragma unroll
  for (int t=0;t<6;t++){
    int d = threadIdx.x + t*256;
    Yb[(size_t)row*DI + d] = f2bf(vals[t]*sc*gnw[d]);
  }
}

// ---------------- final pooling + head -----------------------------------------
__global__ __launch_bounds__(256) void mean_pool(const float* __restrict__ hn,
    float* __restrict__ pooled){
  int idx = blockIdx.x*256+threadIdx.x;
  if (idx >= BATCH*DM) return;
  int b = idx / DM, d = idx % DM;
  float s = 0.f;
  for (int l=0;l<SEQ;l++) s += hn[((size_t)(b*SEQ+l))*DM + d];
  pooled[idx] = s * (1.f/SEQ);
}

__global__ __launch_bounds__(512) void head_k(const float* __restrict__ pooled,
    const float* __restrict__ w1, const float* __restrict__ b1,
    const float* __restrict__ g, const float* __restrict__ bb,
    const float* __restrict__ mn, const float* __restrict__ vr,
    const float* __restrict__ w2, const float* __restrict__ b2,
    float* __restrict__ out){
  int b = blockIdx.x;
  int j = threadIdx.x;
  __shared__ float f[512];
  __shared__ float pl[DM];
  for (int t=j; t<DM; t+=512) pl[t] = pooled[b*DM+t];
  __syncthreads();
  float s = b1[j];
  for (int k=0;k<DM;k++) s += pl[k]*w1[k*512+j];
  s = (s-mn[j])*(g[j]*rsqrtf(vr[j]+EPSF)) + bb[j];
  f[j] = fmaxf(s,0.f);
  __syncthreads();
  if (j < 27){
    float o = b2[j];
    for (int k=0;k<512;k++) o += f[k]*w2[k*27+j];
    out[b*27+j] = o;
  }
}

extern "C" void kernel_launch(void* const* d_in, const int* in_sizes, int n_in,
                              void* d_out, int out_size, void* d_ws, size_t ws_size,
                              hipStream_t stream){
  const float* x      = (const float*)d_in[0];
  const float* c1_w   = (const float*)d_in[1];
  const float* c1_b   = (const float*)d_in[2];
  const float* bn1_g  = (const float*)d_in[3];
  const float* bn1_b  = (const float*)d_in[4];
  const float* bn1_m  = (const float*)d_in[5];
  const float* bn1_v  = (const float*)d_in[6];
  const float* c2_w   = (const float*)d_in[7];
  const float* c2_b   = (const float*)d_in[8];
  const float* bn2_g  = (const float*)d_in[9];
  const float* bn2_b  = (const float*)d_in[10];
  const float* bn2_m  = (const float*)d_in[11];
  const float* bn2_v  = (const float*)d_in[12];
  const float* c3_w   = (const float*)d_in[13];
  const float* c3_b   = (const float*)d_in[14];
  const float* bn3_g  = (const float*)d_in[15];
  const float* bn3_b  = (const float*)d_in[16];
  const float* bn3_m  = (const float*)d_in[17];
  const float* bn3_v  = (const float*)d_in[18];
  const float* ln_w   = (const float*)d_in[19];
  const float* inpw   = (const float*)d_in[20];
  const float* convw  = (const float*)d_in[21];
  const float* convb  = (const float*)d_in[22];
  const float* dtb    = (const float*)d_in[23];
  const float* alog   = (const float*)d_in[24];
  const float* dskip  = (const float*)d_in[25];
  const float* gnw    = (const float*)d_in[26];
  const float* outw   = (const float*)d_in[27];
  const float* normfw = (const float*)d_in[28];
  const float* fc1w   = (const float*)d_in[29];
  const float* fc1b   = (const float*)d_in[30];
  const float* bncg   = (const float*)d_in[31];
  const float* bncb   = (const float*)d_in[32];
  const float* bncm   = (const float*)d_in[33];
  const float* bncv   = (const float*)d_in[34];
  const float* fc2w   = (const float*)d_in[35];
  const float* fc2b   = (const float*)d_in[36];
  (void)in_sizes; (void)n_in; (void)out_size; (void)ws_size;

  char* ws = (char*)d_ws;
  size_t off = 0;
  auto alloc = [&](size_t bytes){
    char* p = ws + off;
    off += (bytes + 255) & ~(size_t)255;
    return (void*)p;
  };
  float* h1  = (float*)alloc((size_t)BATCH*192*LS1*4);
  float* h2  = (float*)alloc((size_t)BATCH*384*LS2*4);
  float* h   = (float*)alloc((size_t)BATCH*SEQ*DM*4);
  float* hn  = (float*)alloc((size_t)BATCH*SEQ*DM*4);
  float* zx  = (float*)alloc((size_t)BATCH*SEQ*PDIM*4);
  float* xbc = (float*)alloc((size_t)BATCH*SEQ*CDIM*4);
  float* dtt = (float*)alloc((size_t)BATCH*NH*SEQ*4);
  float* acs = (float*)alloc((size_t)BATCH*NH*SEQ*4);
  float* st  = (float*)alloc((size_t)BATCH*NCH*NH*HD*DSTATE*4);
  float* pv  = (float*)alloc((size_t)BATCH*NCH*NH*HD*DSTATE*4);
  float* Y   = (float*)alloc((size_t)BATCH*SEQ*DI*4);
  float* pooled = (float*)alloc((size_t)BATCH*DM*4);
  unsigned short* hnb   = (unsigned short*)alloc((size_t)BATCH*SEQ*DM*2);
  unsigned short* Yb    = (unsigned short*)alloc((size_t)BATCH*SEQ*DI*2);
  unsigned short* wtin  = (unsigned short*)alloc((size_t)PPAD*DM*2);       // per-layer (3456,768)
  unsigned short* wtout = (unsigned short*)alloc((size_t)DM*DI*2);         // per-layer (768,1536)

  conv_stem1<<<(BATCH*192*LS1+255)/256,256,0,stream>>>(x, c1_w,c1_b, bn1_g,bn1_b,bn1_m,bn1_v, h1);
  conv_stem2<<<(BATCH*384*LS2+255)/256,256,0,stream>>>(h1, c2_w,c2_b, bn2_g,bn2_b,bn2_m,bn2_v, h2);
  conv_stem3<<<(BATCH*LS2*768+255)/256,256,0,stream>>>(h2, c3_w,c3_b, bn3_g,bn3_b,bn3_m,bn3_v, h);

  const int M = BATCH*SEQ;  // 2048
  for (int l=0; l<NLAYER; l++){
    // weight convert+transpose for this layer
    transpose_cvt<<<dim3(PPAD/32, DM/32),256,0,stream>>>(inpw + (size_t)l*DM*PDIM, wtin, DM, PDIM, PPAD);
    transpose_cvt<<<dim3(DM/32, DI/32),256,0,stream>>>(outw + (size_t)l*DI*DM, wtout, DI, DM, DM);

    rmsnorm768<1><<<M,256,0,stream>>>(h, ln_w + (size_t)l*DM, nullptr, hnb);
    gemm_bf16<0><<<dim3(PPAD/128, M/128),256,0,stream>>>(hnb, wtin, zx, PDIM, DM, PDIM);
    dt_scan<<<BATCH*NH,256,0,stream>>>(zx, dtb + l*NH, alog + l*NH, dtt, acs);
    dwconv<<<(BATCH*SEQ*CDIM+255)/256,256,0,stream>>>(zx, convw + (size_t)l*CDIM*4, convb + (size_t)l*CDIM, xbc);
    ssd_states<<<BATCH*NCH*NH,256,0,stream>>>(xbc, dtt, acs, st);
    ssd_scan<<<(BATCH*NH*HD*DSTATE+255)/256,256,0,stream>>>(st, acs, pv);
    ssd_diag<<<BATCH*NCH*NH,256,0,stream>>>(xbc, dtt, acs, pv, dskip + l*NH, Y);
    gate_rms<<<M,256,0,stream>>>(zx, gnw + (size_t)l*DI, Y, Yb);
    gemm_bf16<1><<<dim3(DM/128, M/128),256,0,stream>>>(Yb, wtout, h, DM, DI, DM);
  }

  rmsnorm768<0><<<M,256,0,stream>>>(h, normfw, hn, nullptr);
  mean_pool<<<(BATCH*DM+255)/256,256,0,stream>>>(hn, pooled);
  head_k<<<BATCH,512,0,stream>>>(pooled, fc1w, fc1b, bncg,bncb,bncm,bncv, fc2w, fc2b, (float*)d_out);
}

// Round 3
// 14013.040 us; speedup vs baseline: 1.9810x; 1.7018x over previous
//
#include <hip/hip_runtime.h>
#include <math.h>

#define DEV __device__ __forceinline__

constexpr int BATCH = 2;
constexpr int L0 = 4096;
constexpr int LS1 = 2048;
constexpr int LS2 = 1024;
constexpr int SEQ = 1024;
constexpr int DM = 768;
constexpr int NH = 24;
constexpr int HD = 64;
constexpr int DI = 1536;
constexpr int DSTATE = 128;
constexpr int CDIM = 1792;   // DI + 2*DSTATE
constexpr int PDIM = 3352;   // 2*DI + 2*DSTATE + NH
constexpr int PPAD = 3456;   // PDIM padded to 27*128
constexpr int CHUNKC = 256;
constexpr int NCH = 4;
constexpr int NLAYER = 24;
constexpr float EPSF = 1e-5f;

typedef short bf16x8 __attribute__((ext_vector_type(8)));
typedef float f32x4 __attribute__((ext_vector_type(4)));

DEV float sigmoidf_(float x){ return 1.f/(1.f+expf(-x)); }
DEV float siluf_(float x){ return x*sigmoidf_(x); }
DEV float geluf_(float x){ return 0.5f*x*(1.f+erff(x*0.70710678118654752440f)); }
DEV float softplusf_(float x){ return fmaxf(x,0.f) + log1pf(expf(-fabsf(x))); }

DEV unsigned short f2bf(float x){
  union { float f; unsigned int u; } v; v.f = x;
  unsigned int u = v.u;
  unsigned int r = (u + 0x7fffu + ((u>>16)&1u)) >> 16;
  return (unsigned short)r;
}

DEV void load_lds16(const void* g, void* l){
  __builtin_amdgcn_global_load_lds(
      (const __attribute__((address_space(1))) unsigned int*)g,
      (__attribute__((address_space(3))) unsigned int*)l,
      16, 0, 0);
}

DEV float block_sum_256(float v, float* red4){
  #pragma unroll
  for (int o=32;o>0;o>>=1) v += __shfl_down(v,o,64);
  int tid = threadIdx.x;
  __syncthreads();
  if ((tid&63)==0) red4[tid>>6]=v;
  __syncthreads();
  return red4[0]+red4[1]+red4[2]+red4[3];
}

// ---------------- stem ----------------
__global__ __launch_bounds__(256) void conv_stem1(const float* __restrict__ x,
    const float* __restrict__ w, const float* __restrict__ bias,
    const float* __restrict__ g, const float* __restrict__ bb,
    const float* __restrict__ mn, const float* __restrict__ vr,
    float* __restrict__ out){
  int idx = blockIdx.x*256+threadIdx.x;
  if (idx >= BATCH*192*LS1) return;
  int lo = idx & (LS1-1);
  int co = (idx >> 11) % 192;
  int b  = idx / (192*LS1);
  float s = bias[co];
  const float* wr = w + co*60;
  #pragma unroll
  for (int ci=0; ci<12; ci++){
    const float* xr = x + ((size_t)(b*12+ci))*L0;
    #pragma unroll
    for (int k=0;k<5;k++){
      int li = lo*2 + k - 2;
      if (li>=0 && li<L0) s += wr[ci*5+k]*xr[li];
    }
  }
  s = geluf_(s);
  s = (s-mn[co])*(g[co]*rsqrtf(vr[co]+EPSF)) + bb[co];
  out[idx] = s;
}

__global__ __launch_bounds__(256) void conv_stem2(const float* __restrict__ x,
    const float* __restrict__ w, const float* __restrict__ bias,
    const float* __restrict__ g, const float* __restrict__ bb,
    const float* __restrict__ mn, const float* __restrict__ vr,
    float* __restrict__ out){
  int idx = blockIdx.x*256+threadIdx.x;
  if (idx >= BATCH*384*LS2) return;
  int lo = idx & (LS2-1);
  int co = (idx >> 10) % 384;
  int b  = idx / (384*LS2);
  float s = bias[co];
  const float* wr = w + co*(192*3);
  const float* xb = x + (size_t)b*192*LS1;
  for (int ci=0; ci<192; ci++){
    const float* base = xb + ci*LS1;
    int l2 = lo*2;
    s += wr[ci*3+1]*base[l2];
    s += wr[ci*3+2]*base[l2+1];
    if (lo>0) s += wr[ci*3]*base[l2-1];
  }
  s = geluf_(s);
  s = (s-mn[co])*(g[co]*rsqrtf(vr[co]+EPSF)) + bb[co];
  out[idx] = s;
}

__global__ __launch_bounds__(256) void conv_stem3(const float* __restrict__ x,
    const float* __restrict__ w, const float* __restrict__ bias,
    const float* __restrict__ g, const float* __restrict__ bb,
    const float* __restrict__ mn, const float* __restrict__ vr,
    float* __restrict__ h){
  int idx = blockIdx.x*256+threadIdx.x;
  if (idx >= BATCH*LS2*768) return;
  int co = idx % 768;
  int lo = (idx/768) % LS2;
  int b  = idx / (768*LS2);
  float s = bias[co];
  const float* wr = w + (size_t)co*384*3;
  const float* xb = x + (size_t)b*384*LS2;
  for (int ci=0; ci<384; ci++){
    const float* xr = xb + ci*LS2 + lo;
    s += wr[ci*3+1]*xr[0];
    if (lo>0)     s += wr[ci*3]*xr[-1];
    if (lo<LS2-1) s += wr[ci*3+2]*xr[1];
  }
  s = geluf_(s);
  s = (s-mn[co])*(g[co]*rsqrtf(vr[co]+EPSF)) + bb[co];
  h[((size_t)(b*SEQ+lo))*DM + co] = s;
}

// ---------------- rmsnorm (D=768), optional bf16 output ----------------
template<int BF>
__global__ __launch_bounds__(256) void rmsnorm768(const float* __restrict__ in,
    const float* __restrict__ w, float* __restrict__ outf, unsigned short* __restrict__ outb){
  int row = blockIdx.x;
  const float* p = in + (size_t)row*DM;
  float v0[3]; float ss=0.f;
  #pragma unroll
  for (int t=0;t<3;t++){ float q = p[threadIdx.x + t*256]; v0[t]=q; ss+=q*q; }
  __shared__ float red[4];
  float tot = block_sum_256(ss, red);
  float sc = rsqrtf(tot*(1.f/DM) + EPSF);
  #pragma unroll
  for (int t=0;t<3;t++){
    int d = threadIdx.x + t*256;
    float o = v0[t]*sc*w[d];
    if (BF) outb[(size_t)row*DM + d] = f2bf(o);
    else    outf[(size_t)row*DM + d] = o;
  }
}

// ---------------- transpose + fp32->bf16 convert: in (R,Cin) -> out (Cpad,R) ---
__global__ __launch_bounds__(256) void transpose_cvt(const float* __restrict__ in,
    unsigned short* __restrict__ out, int R, int Cin, int Cpad){
  __shared__ float t[32][33];
  int c0 = blockIdx.x*32, r0 = blockIdx.y*32;
  int tx = threadIdx.x & 31, ty = threadIdx.x >> 5;   // 32 x 8
  #pragma unroll
  for (int i=0;i<32;i+=8){
    int r = r0+ty+i, c = c0+tx;
    t[ty+i][tx] = (c<Cin) ? in[(size_t)r*Cin + c] : 0.f;
  }
  __syncthreads();
  #pragma unroll
  for (int i=0;i<32;i+=8){
    int c = c0+ty+i, r = r0+tx;
    if (c < Cpad) out[(size_t)c*R + r] = f2bf(t[tx][ty+i]);
  }
}

// ---------------- bf16 MFMA GEMM: C[M,Ntrue] (+)= A[M,K] @ Bt[N,K]^T -----------
template<int ACCUM>
__global__ __launch_bounds__(256,2) void gemm_bf16(const unsigned short* __restrict__ A,
    const unsigned short* __restrict__ Bt, float* __restrict__ C,
    int Ntrue, int K, int ldc){
  __shared__ alignas(16) unsigned short As[128*32];
  __shared__ alignas(16) unsigned short Bs[128*32];
  int tid = threadIdx.x;
  int wave = tid >> 6, lane = tid & 63;
  int mBase = blockIdx.y*128, nBase = blockIdx.x*128;
  const size_t K2 = (size_t)K*2;
  int o0 = wave*1024 + lane*16;
  int o1 = o0 + 4096;
  const char* Ag0 = (const char*)A + (size_t)(mBase + (o0>>6))*K2 + (o0&63);
  const char* Ag1 = (const char*)A + (size_t)(mBase + (o1>>6))*K2 + (o1&63);
  const char* Bg0 = (const char*)Bt + (size_t)(nBase + (o0>>6))*K2 + (o0&63);
  const char* Bg1 = (const char*)Bt + (size_t)(nBase + (o1>>6))*K2 + (o1&63);
  char* AsW = (char*)As + wave*1024;
  char* BsW = (char*)Bs + wave*1024;

  int wm = (wave>>1)*64, wn = (wave&1)*64;
  int ln = lane & 15, quad = lane >> 4;

  f32x4 acc[4][4];
  #pragma unroll
  for (int i=0;i<4;i++)
    #pragma unroll
    for (int j=0;j<4;j++) acc[i][j] = (f32x4){0.f,0.f,0.f,0.f};

  for (int k0=0; k0<K; k0+=32){
    size_t kb = (size_t)k0*2;
    __syncthreads();
    load_lds16(Ag0 + kb, AsW);
    load_lds16(Ag1 + kb, AsW + 4096);
    load_lds16(Bg0 + kb, BsW);
    load_lds16(Bg1 + kb, BsW + 4096);
    __syncthreads();
    bf16x8 a[4], b[4];
    #pragma unroll
    for (int mt=0;mt<4;mt++)
      a[mt] = *(const bf16x8*)((const char*)As + (size_t)(wm+mt*16+ln)*64 + quad*16);
    #pragma unroll
    for (int nt=0;nt<4;nt++)
      b[nt] = *(const bf16x8*)((const char*)Bs + (size_t)(wn+nt*16+ln)*64 + quad*16);
    #pragma unroll
    for (int mt=0;mt<4;mt++)
      #pragma unroll
      for (int nt=0;nt<4;nt++)
        acc[mt][nt] = __builtin_amdgcn_mfma_f32_16x16x32_bf16(a[mt], b[nt], acc[mt][nt], 0,0,0);
  }

  #pragma unroll
  for (int mt=0;mt<4;mt++){
    #pragma unroll
    for (int nt=0;nt<4;nt++){
      int col = nBase + wn + nt*16 + ln;
      int row0 = mBase + wm + mt*16 + quad*4;
      if (col < Ntrue){
        #pragma unroll
        for (int r=0;r<4;r++){
          float* p = C + (size_t)(row0+r)*ldc + col;
          float v = acc[mt][nt][r];
          if (ACCUM) v += *p;
          *p = v;
        }
      }
    }
  }
}

// ---------------- dt cumsum ----------------
__global__ __launch_bounds__(256) void dt_scan(const float* __restrict__ zx,
    const float* __restrict__ dtb, const float* __restrict__ alog,
    float* __restrict__ dtt, float* __restrict__ acs){
  int b = blockIdx.x / NH, h = blockIdx.x % NH;
  int tid = threadIdx.x;
  float negA = -expf(alog[h]);
  float bias = dtb[h];
  __shared__ float sc[256];
  for (int c=0;c<NCH;c++){
    int l = c*CHUNKC + tid;
    float xv = zx[((size_t)(b*SEQ+l))*PDIM + (DI+CDIM) + h] + bias;
    float dt = softplusf_(xv);
    float v = dt*negA;
    sc[tid]=v; __syncthreads();
    #pragma unroll
    for (int off=1; off<256; off<<=1){
      float t = (tid>=off)? sc[tid-off]:0.f;
      __syncthreads();
      v += t; sc[tid]=v;
      __syncthreads();
    }
    dtt[(b*NH+h)*SEQ + l] = dt;
    acs[(b*NH+h)*SEQ + l] = v;
  }
}

// ---------------- depthwise causal conv (K=4) + SiLU ------------
__global__ __launch_bounds__(256) void dwconv(const float* __restrict__ zx,
    const float* __restrict__ w, const float* __restrict__ bias,
    float* __restrict__ out){
  int idx = blockIdx.x*256+threadIdx.x;
  if (idx >= BATCH*SEQ*CDIM) return;
  int c = idx % CDIM;
  int l = (idx/CDIM) % SEQ;
  int b = idx / (CDIM*SEQ);
  float s = bias[c];
  const float* col = zx + (size_t)(b*SEQ)*PDIM + DI + c;
  #pragma unroll
  for (int k=0;k<4;k++){
    int li = l-3+k;
    if (li>=0) s += w[c*4+k]*col[(size_t)li*PDIM];
  }
  out[idx] = siluf_(s);
}

// ---------------- SSD: chunk states (scalar, no spill risk) ----------------
__global__ __launch_bounds__(256) void ssd_states(const float* __restrict__ xbc,
    const float* __restrict__ dtt, const float* __restrict__ acs,
    float* __restrict__ states){
  int blk = blockIdx.x;
  int h = blk % NH, c = (blk/NH) % NCH, b = blk/(NH*NCH);
  int tid = threadIdx.x;
  __shared__ float bs[32][DSTATE];
  __shared__ float xs[32][HD];
  __shared__ float dec[32];
  float acs_last = acs[(b*NH+h)*SEQ + c*CHUNKC + CHUNKC-1];
  int p = tid & 63, ng = tid >> 6;
  float accv[32];
  #pragma unroll
  for (int nn=0;nn<32;nn++) accv[nn]=0.f;
  for (int jt=0; jt<CHUNKC/32; jt++){
    __syncthreads();
    for (int t=tid; t<32*32; t+=256){
      int jj = t >> 5, q = t & 31;
      int lj = c*CHUNKC + jt*32 + jj;
      ((float4*)&bs[jj][0])[q] = *(const float4*)(xbc + ((size_t)(b*SEQ+lj))*CDIM + DI + q*4);
    }
    for (int t=tid; t<32*16; t+=256){
      int jj = t >> 4, q = t & 15;
      int lj = c*CHUNKC + jt*32 + jj;
      float d = dtt[(b*NH+h)*SEQ + lj];
      float4 v = *(const float4*)(xbc + ((size_t)(b*SEQ+lj))*CDIM + h*HD + q*4);
      v.x*=d; v.y*=d; v.z*=d; v.w*=d;
      ((float4*)&xs[jj][0])[q] = v;
    }
    if (tid < 32){
      int lj = c*CHUNKC + jt*32 + tid;
      dec[tid] = expf(acs_last - acs[(b*NH+h)*SEQ + lj]);
    }
    __syncthreads();
    for (int jj=0;jj<32;jj++){
      float f = dec[jj]*xs[jj][p];
      const float* br = &bs[jj][ng*32];
      #pragma unroll
      for (int nn=0;nn<32;nn++) accv[nn] += f*br[nn];
    }
  }
  float* sp = states + (((size_t)(b*NCH+c)*NH + h) << 13) + p*DSTATE + ng*32;
  #pragma unroll
  for (int nn=0;nn<32;nn++) sp[nn] = accv[nn];
}

// ---------------- inter-chunk scan ----------------
__global__ __launch_bounds__(256) void ssd_scan(const float* __restrict__ states,
    const float* __restrict__ acs, float* __restrict__ prev){
  int idx = blockIdx.x*256+threadIdx.x;
  if (idx >= BATCH*NH*HD*DSTATE) return;
  int pn = idx & 8191;
  int bh = idx >> 13;
  int h = bh % NH, b = bh / NH;
  float carry = 0.f;
  #pragma unroll
  for (int c=0;c<NCH;c++){
    size_t o = (((size_t)(b*NCH+c)*NH + h) << 13) + pn;
    prev[o] = carry;
    float dec = expf(acs[(b*NH+h)*SEQ + c*CHUNKC + CHUNKC-1]);
    carry = carry*dec + states[o];
  }
}

// ---------------- SSD diag + off-diag + skip via MFMA --------------------------
// block = (b,c,h,t): 64-row strip of chunk c. 4 waves x 16 rows.
constexpr int CW_S  = 136;  // shorts: 128-col bf16 tiles, padded (+8 keeps 16B align)
constexpr int XDT_S = 72;   // shorts: XdT rows (64 cols + pad)
constexpr int XF_S  = 68;   // floats: Xf staging rows (64 cols + pad, 16B-aligned rows)
constexpr int SB_S  = 72;   // shorts: per-wave S tile rows

__global__ __launch_bounds__(256,2) void ssd_diag_mfma(
    const float* __restrict__ xbc, const float* __restrict__ dtt,
    const float* __restrict__ acs, const float* __restrict__ prev,
    const float* __restrict__ dskip, float* __restrict__ Y){
  int blk = blockIdx.x;
  int t = blk & 3;
  int r0 = blk >> 2;
  int h = r0 % NH;  r0 /= NH;
  int c = r0 % NCH;
  int b = r0 / NCH;

  int tid = threadIdx.x;
  int wave = tid>>6, lane = tid&63, ln = lane&15, quad = lane>>4;

  __shared__ float ac[CHUNKC];                           // 1 KB
  __shared__ alignas(16) unsigned short Cw[64*CW_S];     // 17408 B
  __shared__ alignas(16) unsigned short Pv[64*CW_S];     // 17408 B
  __shared__ alignas(16) unsigned short XdT[64*XDT_S];   // 9216 B
  __shared__ alignas(16) unsigned short Sb[4][16*SB_S];  // 9216 B
  __shared__ alignas(16) char uBX[64*CW_S*2];            // 17408 B: union Bt(bf16)/Xf(f32)
  unsigned short* Bt = (unsigned short*)uBX;
  float* Xf = (float*)uBX;

  const int bh = b*NH + h;
  const size_t rowbase = (size_t)(b*SEQ + c*CHUNKC);

  ac[tid] = acs[(size_t)bh*SEQ + c*CHUNKC + tid];

  // stage C strip (rows t*64..t*64+63) and prev, both -> bf16
  const float* pvsrc = prev + (((size_t)(b*NCH+c)*NH + h) << 13);
  for (int idx=tid; idx<2048; idx+=256){
    int row = idx>>5, nq = idx&31;
    float4 v = *(const float4*)(xbc + (rowbase + t*64 + row)*CDIM + DI + DSTATE + nq*4);
    ushort4 u; u.x=f2bf(v.x); u.y=f2bf(v.y); u.z=f2bf(v.z); u.w=f2bf(v.w);
    *(ushort4*)&Cw[row*CW_S + nq*4] = u;
    float4 w = *(const float4*)(pvsrc + (size_t)row*DSTATE + nq*4);
    ushort4 uw; uw.x=f2bf(w.x); uw.y=f2bf(w.y); uw.z=f2bf(w.z); uw.w=f2bf(w.w);
    *(ushort4*)&Pv[row*CW_S + nq*4] = uw;
  }
  __syncthreads();

  // A-fragments of C (wave's 16 rows), K=128 in 4 chunks of 32
  bf16x8 aC[4];
  #pragma unroll
  for (int kq=0;kq<4;kq++)
    aC[kq] = *(const bf16x8*)&Cw[(wave*16+ln)*CW_S + kq*32 + quad*8];

  f32x4 yacc[4];
  #pragma unroll
  for (int ps=0;ps<4;ps++) yacc[ps] = (f32x4){0.f,0.f,0.f,0.f};

  for (int jt=0; jt<=t; jt++){
    __syncthreads();
    // stage Xd (=X*dt) fp32 into Xf (row j, col p)
    for (int idx=tid; idx<1024; idx+=256){
      int jl = idx>>4, pq = idx&15;
      float d = dtt[(size_t)bh*SEQ + c*CHUNKC + jt*64 + jl];
      float4 v = *(const float4*)(xbc + (rowbase + jt*64 + jl)*CDIM + h*HD + pq*4);
      v.x*=d; v.y*=d; v.z*=d; v.w*=d;
      *(float4*)&Xf[jl*XF_S + pq*4] = v;
    }
    __syncthreads();
    // transpose Xf -> XdT (row p, col j) bf16
    {
      int p = tid>>2, jq = tid&3;
      #pragma unroll
      for (int ji=0; ji<16; ji++){
        int j = jq*16+ji;
        XdT[p*XDT_S + j] = f2bf(Xf[j*XF_S + p]);
      }
    }
    __syncthreads();
    // stage B tile (rows jt*64.., cols n 0..127) bf16 (overwrites Xf)
    for (int idx=tid; idx<2048; idx+=256){
      int row = idx>>5, nq = idx&31;
      float4 v = *(const float4*)(xbc + (rowbase + jt*64 + row)*CDIM + DI + nq*4);
      ushort4 u; u.x=f2bf(v.x); u.y=f2bf(v.y); u.z=f2bf(v.z); u.w=f2bf(v.w);
    *(ushort4*)&Bt[row*CW_S + nq*4] = u;
    }
    __syncthreads();

    // S = C.B^T for this wave's 16 rows x 64 cols; scale by L-mask; store bf16
    #pragma unroll
    for (int js=0; js<4; js++){
      f32x4 s = (f32x4){0.f,0.f,0.f,0.f};
      #pragma unroll
      for (int kq=0;kq<4;kq++){
        bf16x8 bB = *(const bf16x8*)&Bt[(js*16+ln)*CW_S + kq*32 + quad*8];
        s = __builtin_amdgcn_mfma_f32_16x16x32_bf16(aC[kq], bB, s, 0,0,0);
      }
      int jc = jt*64 + js*16 + ln;
      #pragma unroll
      for (int r=0;r<4;r++){
        int icl = t*64 + wave*16 + quad*4 + r;
        float d = (jc<=icl) ? (ac[icl]-ac[jc]) : -1e30f;
        Sb[wave][(quad*4+r)*SB_S + js*16 + ln] = f2bf(expf(d)*s[r]);
      }
    }
    // PV: Y += S(16x64) . Xd(64x64)  — per-wave Sb, no barrier needed
    bf16x8 aS[2];
    #pragma unroll
    for (int kq=0;kq<2;kq++)
      aS[kq] = *(const bf16x8*)&Sb[wave][ln*SB_S + kq*32 + quad*8];
    #pragma unroll
    for (int ps=0;ps<4;ps++){
      #pragma unroll
      for (int kq=0;kq<2;kq++){
        bf16x8 bX = *(const bf16x8*)&XdT[(ps*16+ln)*XDT_S + kq*32 + quad*8];
        yacc[ps] = __builtin_amdgcn_mfma_f32_16x16x32_bf16(aS[kq], bX, yacc[ps], 0,0,0);
      }
    }
  }

  // off-diag: exp(acs_i) * C . prev^T
  f32x4 oacc[4];
  #pragma unroll
  for (int ps=0;ps<4;ps++) oacc[ps] = (f32x4){0.f,0.f,0.f,0.f};
  #pragma unroll
  for (int ps=0;ps<4;ps++){
    #pragma unroll
    for (int kq=0;kq<4;kq++){
      bf16x8 bP = *(const bf16x8*)&Pv[(ps*16+ln)*CW_S + kq*32 + quad*8];
      oacc[ps] = __builtin_amdgcn_mfma_f32_16x16x32_bf16(aC[kq], bP, oacc[ps], 0,0,0);
    }
  }

  float dsk = dskip[h];
  #pragma unroll
  for (int r=0;r<4;r++){
    int icl = t*64 + wave*16 + quad*4 + r;
    float ei = expf(ac[icl]);
    size_t l = rowbase + icl;
    #pragma unroll
    for (int ps=0;ps<4;ps++){
      int p = ps*16 + ln;
      float xraw = xbc[l*CDIM + h*HD + p];
      Y[l*DI + h*HD + p] = yacc[ps][r] + ei*oacc[ps][r] + dsk*xraw;
    }
  }
}

// ---------------- gate (silu(z)) + rmsnorm over 1536 -> bf16 ------------
__global__ __launch_bounds__(256) void gate_rms(const float* __restrict__ zx,
    const float* __restrict__ gnw, const float* __restrict__ Y,
    unsigned short* __restrict__ Yb){
  int row = blockIdx.x;
  const float* z = zx + (size_t)row*PDIM;
  const float* y = Y + (size_t)row*DI;
  float vals[6]; float ss=0.f;
  #pragma unroll
  for (int t=0;t<6;t++){
    int d = threadIdx.x + t*256;
    float v = y[d]*siluf_(z[d]);
    vals[t]=v; ss+=v*v;
  }
  __shared__ float red[4];
  float tot = block_sum_256(ss, red);
  float sc = rsqrtf(tot*(1.f/DI)+EPSF);
  #pragma unroll
  for (int t=0;t<6;t++){
    int d = threadIdx.x + t*256;
    Yb[(size_t)row*DI + d] = f2bf(vals[t]*sc*gnw[d]);
  }
}

// ---------------- final pooling + head -----------------------------------------
__global__ __launch_bounds__(256) void mean_pool(const float* __restrict__ hn,
    float* __restrict__ pooled){
  int idx = blockIdx.x*256+threadIdx.x;
  if (idx >= BATCH*DM) return;
  int b = idx / DM, d = idx % DM;
  float s = 0.f;
  for (int l=0;l<SEQ;l++) s += hn[((size_t)(b*SEQ+l))*DM + d];
  pooled[idx] = s * (1.f/SEQ);
}

__global__ __launch_bounds__(512) void head_k(const float* __restrict__ pooled,
    const float* __restrict__ w1, const float* __restrict__ b1,
    const float* __restrict__ g, const float* __restrict__ bb,
    const float* __restrict__ mn, const float* __restrict__ vr,
    const float* __restrict__ w2, const float* __restrict__ b2,
    float* __restrict__ out){
  int b = blockIdx.x;
  int j = threadIdx.x;
  __shared__ float f[512];
  __shared__ float pl[DM];
  for (int t=j; t<DM; t+=512) pl[t] = pooled[b*DM+t];
  __syncthreads();
  float s = b1[j];
  for (int k=0;k<DM;k++) s += pl[k]*w1[k*512+j];
  s = (s-mn[j])*(g[j]*rsqrtf(vr[j]+EPSF)) + bb[j];
  f[j] = fmaxf(s,0.f);
  __syncthreads();
  if (j < 27){
    float o = b2[j];
    for (int k=0;k<512;k++) o += f[k]*w2[k*27+j];
    out[b*27+j] = o;
  }
}

extern "C" void kernel_launch(void* const* d_in, const int* in_sizes, int n_in,
                              void* d_out, int out_size, void* d_ws, size_t ws_size,
                              hipStream_t stream){
  const float* x      = (const float*)d_in[0];
  const float* c1_w   = (const float*)d_in[1];
  const float* c1_b   = (const float*)d_in[2];
  const float* bn1_g  = (const float*)d_in[3];
  const float* bn1_b  = (const float*)d_in[4];
  const float* bn1_m  = (const float*)d_in[5];
  const float* bn1_v  = (const float*)d_in[6];
  const float* c2_w   = (const float*)d_in[7];
  const float* c2_b   = (const float*)d_in[8];
  const float* bn2_g  = (const float*)d_in[9];
  const float* bn2_b  = (const float*)d_in[10];
  const float* bn2_m  = (const float*)d_in[11];
  const float* bn2_v  = (const float*)d_in[12];
  const float* c3_w   = (const float*)d_in[13];
  const float* c3_b   = (const float*)d_in[14];
  const float* bn3_g  = (const float*)d_in[15];
  const float* bn3_b  = (const float*)d_in[16];
  const float* bn3_m  = (const float*)d_in[17];
  const float* bn3_v  = (const float*)d_in[18];
  const float* ln_w   = (const float*)d_in[19];
  const float* inpw   = (const float*)d_in[20];
  const float* convw  = (const float*)d_in[21];
  const float* convb  = (const float*)d_in[22];
  const float* dtb    = (const float*)d_in[23];
  const float* alog   = (const float*)d_in[24];
  const float* dskip  = (const float*)d_in[25];
  const float* gnw    = (const float*)d_in[26];
  const float* outw   = (const float*)d_in[27];
  const float* normfw = (const float*)d_in[28];
  const float* fc1w   = (const float*)d_in[29];
  const float* fc1b   = (const float*)d_in[30];
  const float* bncg   = (const float*)d_in[31];
  const float* bncb   = (const float*)d_in[32];
  const float* bncm   = (const float*)d_in[33];
  const float* bncv   = (const float*)d_in[34];
  const float* fc2w   = (const float*)d_in[35];
  const float* fc2b   = (const float*)d_in[36];
  (void)in_sizes; (void)n_in; (void)out_size; (void)ws_size;

  char* ws = (char*)d_ws;
  size_t off = 0;
  auto alloc = [&](size_t bytes){
    char* p = ws + off;
    off += (bytes + 255) & ~(size_t)255;
    return (void*)p;
  };
  float* h1  = (float*)alloc((size_t)BATCH*192*LS1*4);
  float* h2  = (float*)alloc((size_t)BATCH*384*LS2*4);
  float* h   = (float*)alloc((size_t)BATCH*SEQ*DM*4);
  float* hn  = (float*)alloc((size_t)BATCH*SEQ*DM*4);
  float* zx  = (float*)alloc((size_t)BATCH*SEQ*PDIM*4);
  float* xbc = (float*)alloc((size_t)BATCH*SEQ*CDIM*4);
  float* dtt = (float*)alloc((size_t)BATCH*NH*SEQ*4);
  float* acs = (float*)alloc((size_t)BATCH*NH*SEQ*4);
  float* st  = (float*)alloc((size_t)BATCH*NCH*NH*HD*DSTATE*4);
  float* pv  = (float*)alloc((size_t)BATCH*NCH*NH*HD*DSTATE*4);
  float* Y   = (float*)alloc((size_t)BATCH*SEQ*DI*4);
  float* pooled = (float*)alloc((size_t)BATCH*DM*4);
  unsigned short* hnb   = (unsigned short*)alloc((size_t)BATCH*SEQ*DM*2);
  unsigned short* Yb    = (unsigned short*)alloc((size_t)BATCH*SEQ*DI*2);
  unsigned short* wtin  = (unsigned short*)alloc((size_t)PPAD*DM*2);
  unsigned short* wtout = (unsigned short*)alloc((size_t)DM*DI*2);

  conv_stem1<<<(BATCH*192*LS1+255)/256,256,0,stream>>>(x, c1_w,c1_b, bn1_g,bn1_b,bn1_m,bn1_v, h1);
  conv_stem2<<<(BATCH*384*LS2+255)/256,256,0,stream>>>(h1, c2_w,c2_b, bn2_g,bn2_b,bn2_m,bn2_v, h2);
  conv_stem3<<<(BATCH*LS2*768+255)/256,256,0,stream>>>(h2, c3_w,c3_b, bn3_g,bn3_b,bn3_m,bn3_v, h);

  const int M = BATCH*SEQ;  // 2048
  for (int l=0; l<NLAYER; l++){
    transpose_cvt<<<dim3(PPAD/32, DM/32),256,0,stream>>>(inpw + (size_t)l*DM*PDIM, wtin, DM, PDIM, PPAD);
    transpose_cvt<<<dim3(DM/32, DI/32),256,0,stream>>>(outw + (size_t)l*DI*DM, wtout, DI, DM, DM);

    rmsnorm768<1><<<M,256,0,stream>>>(h, ln_w + (size_t)l*DM, nullptr, hnb);
    gemm_bf16<0><<<dim3(PPAD/128, M/128),256,0,stream>>>(hnb, wtin, zx, PDIM, DM, PDIM);
    dt_scan<<<BATCH*NH,256,0,stream>>>(zx, dtb + l*NH, alog + l*NH, dtt, acs);
    dwconv<<<(BATCH*SEQ*CDIM+255)/256,256,0,stream>>>(zx, convw + (size_t)l*CDIM*4, convb + (size_t)l*CDIM, xbc);
    ssd_states<<<BATCH*NCH*NH,256,0,stream>>>(xbc, dtt, acs, st);
    ssd_scan<<<(BATCH*NH*HD*DSTATE+255)/256,256,0,stream>>>(st, acs, pv);
    ssd_diag_mfma<<<BATCH*NCH*NH*4,256,0,stream>>>(xbc, dtt, acs, pv, dskip + l*NH, Y);
    gate_rms<<<M,256,0,stream>>>(zx, gnw + (size_t)l*DI, Y, Yb);
    gemm_bf16<1><<<dim3(DM/128, M/128),256,0,stream>>>(Yb, wtout, h, DM, DI, DM);
  }

  rmsnorm768<0><<<M,256,0,stream>>>(h, normfw, hn, nullptr);
  mean_pool<<<(BATCH*DM+255)/256,256,0,stream>>>(hn, pooled);
  head_k<<<BATCH,512,0,stream>>>(pooled, fc1w, fc1b, bncg,bncb,bncm,bncv, fc2w, fc2b, (float*)d_out);
}

// Round 4
// 5989.987 us; speedup vs baseline: 4.6343x; 2.3394x over previous
//
#include <hip/hip_runtime.h>
#include <math.h>

#define DEV __device__ __forceinline__

constexpr int BATCH = 2;
constexpr int L0 = 4096;
constexpr int LS1 = 2048;
constexpr int LS2 = 1024;
constexpr int SEQ = 1024;
constexpr int DM = 768;
constexpr int NH = 24;
constexpr int HD = 64;
constexpr int DI = 1536;
constexpr int DSTATE = 128;
constexpr int CDIM = 1792;   // DI + 2*DSTATE
constexpr int PDIM = 3352;   // 2*DI + 2*DSTATE + NH
constexpr int PPAD = 3456;   // PDIM padded to 27*128
constexpr int CHUNKC = 256;
constexpr int NCH = 4;
constexpr int NLAYER = 24;
constexpr float EPSF = 1e-5f;

typedef short bf16x8 __attribute__((ext_vector_type(8)));
typedef float f32x4 __attribute__((ext_vector_type(4)));

DEV float sigmoidf_(float x){ return 1.f/(1.f+expf(-x)); }
DEV float siluf_(float x){ return x*sigmoidf_(x); }
DEV float geluf_(float x){ return 0.5f*x*(1.f+erff(x*0.70710678118654752440f)); }
DEV float softplusf_(float x){ return fmaxf(x,0.f) + log1pf(expf(-fabsf(x))); }

DEV unsigned short f2bf(float x){
  union { float f; unsigned int u; } v; v.f = x;
  unsigned int u = v.u;
  unsigned int r = (u + 0x7fffu + ((u>>16)&1u)) >> 16;
  return (unsigned short)r;
}

DEV void load_lds16(const void* g, void* l){
  __builtin_amdgcn_global_load_lds(
      (const __attribute__((address_space(1))) unsigned int*)g,
      (__attribute__((address_space(3))) unsigned int*)l,
      16, 0, 0);
}

DEV float block_sum_256(float v, float* red4){
  #pragma unroll
  for (int o=32;o>0;o>>=1) v += __shfl_down(v,o,64);
  int tid = threadIdx.x;
  __syncthreads();
  if ((tid&63)==0) red4[tid>>6]=v;
  __syncthreads();
  return red4[0]+red4[1]+red4[2]+red4[3];
}

// ---------------- stem ----------------
__global__ __launch_bounds__(256) void conv_stem1(const float* __restrict__ x,
    const float* __restrict__ w, const float* __restrict__ bias,
    const float* __restrict__ g, const float* __restrict__ bb,
    const float* __restrict__ mn, const float* __restrict__ vr,
    float* __restrict__ out){
  int idx = blockIdx.x*256+threadIdx.x;
  if (idx >= BATCH*192*LS1) return;
  int lo = idx & (LS1-1);
  int co = (idx >> 11) % 192;
  int b  = idx / (192*LS1);
  float s = bias[co];
  const float* wr = w + co*60;
  #pragma unroll
  for (int ci=0; ci<12; ci++){
    const float* xr = x + ((size_t)(b*12+ci))*L0;
    #pragma unroll
    for (int k=0;k<5;k++){
      int li = lo*2 + k - 2;
      if (li>=0 && li<L0) s += wr[ci*5+k]*xr[li];
    }
  }
  s = geluf_(s);
  s = (s-mn[co])*(g[co]*rsqrtf(vr[co]+EPSF)) + bb[co];
  out[idx] = s;
}

__global__ __launch_bounds__(256) void conv_stem2(const float* __restrict__ x,
    const float* __restrict__ w, const float* __restrict__ bias,
    const float* __restrict__ g, const float* __restrict__ bb,
    const float* __restrict__ mn, const float* __restrict__ vr,
    float* __restrict__ out){
  int idx = blockIdx.x*256+threadIdx.x;
  if (idx >= BATCH*384*LS2) return;
  int lo = idx & (LS2-1);
  int co = (idx >> 10) % 384;
  int b  = idx / (384*LS2);
  float s = bias[co];
  const float* wr = w + co*(192*3);
  const float* xb = x + (size_t)b*192*LS1;
  for (int ci=0; ci<192; ci++){
    const float* base = xb + ci*LS1;
    int l2 = lo*2;
    s += wr[ci*3+1]*base[l2];
    s += wr[ci*3+2]*base[l2+1];
    if (lo>0) s += wr[ci*3]*base[l2-1];
  }
  s = geluf_(s);
  s = (s-mn[co])*(g[co]*rsqrtf(vr[co]+EPSF)) + bb[co];
  out[idx] = s;
}

// conv3: one block per (b,co); weights cached in LDS (broadcast), x coalesced over lo
__global__ __launch_bounds__(256) void conv_stem3(const float* __restrict__ x,
    const float* __restrict__ w, const float* __restrict__ bias,
    const float* __restrict__ g, const float* __restrict__ bb,
    const float* __restrict__ mn, const float* __restrict__ vr,
    float* __restrict__ h){
  int co = blockIdx.x % 768;
  int b  = blockIdx.x / 768;
  __shared__ float wsh[384*3];
  for (int t=threadIdx.x; t<384*3; t+=256) wsh[t] = w[(size_t)co*1152 + t];
  __syncthreads();
  const float* xb = x + (size_t)b*384*LS2;
  float scale = g[co]*rsqrtf(vr[co]+EPSF);
  float bnb = bb[co], bnm = mn[co], bs0 = bias[co];
  #pragma unroll
  for (int s=0;s<4;s++){
    int lo = s*256 + threadIdx.x;
    int offm = (lo>0)? -1 : 0;        float mm = (lo>0)? 1.f : 0.f;
    int offp = (lo<LS2-1)? 1 : 0;     float mp = (lo<LS2-1)? 1.f : 0.f;
    float acc = bs0;
    for (int ci=0; ci<384; ci++){
      const float* xr = xb + ci*LS2 + lo;
      float w0=wsh[ci*3+0], w1=wsh[ci*3+1], w2=wsh[ci*3+2];
      acc += w1*xr[0];
      acc += mm*w0*xr[offm];
      acc += mp*w2*xr[offp];
    }
    acc = geluf_(acc);
    acc = (acc-bnm)*scale + bnb;
    h[((size_t)(b*SEQ+lo))*DM + co] = acc;
  }
}

// ---------------- rmsnorm (D=768), optional bf16 output ----------------
template<int BF>
__global__ __launch_bounds__(256) void rmsnorm768(const float* __restrict__ in,
    const float* __restrict__ w, float* __restrict__ outf, unsigned short* __restrict__ outb){
  int row = blockIdx.x;
  const float* p = in + (size_t)row*DM;
  float v0[3]; float ss=0.f;
  #pragma unroll
  for (int t=0;t<3;t++){ float q = p[threadIdx.x + t*256]; v0[t]=q; ss+=q*q; }
  __shared__ float red[4];
  float tot = block_sum_256(ss, red);
  float sc = rsqrtf(tot*(1.f/DM) + EPSF);
  #pragma unroll
  for (int t=0;t<3;t++){
    int d = threadIdx.x + t*256;
    float o = v0[t]*sc*w[d];
    if (BF) outb[(size_t)row*DM + d] = f2bf(o);
    else    outf[(size_t)row*DM + d] = o;
  }
}

// ---------------- transpose + fp32->bf16 convert: in (R,Cin) -> out (Cpad,R) ---
__global__ __launch_bounds__(256) void transpose_cvt(const float* __restrict__ in,
    unsigned short* __restrict__ out, int R, int Cin, int Cpad){
  __shared__ float t[32][33];
  int c0 = blockIdx.x*32, r0 = blockIdx.y*32;
  int tx = threadIdx.x & 31, ty = threadIdx.x >> 5;   // 32 x 8
  #pragma unroll
  for (int i=0;i<32;i+=8){
    int r = r0+ty+i, c = c0+tx;
    t[ty+i][tx] = (c<Cin) ? in[(size_t)r*Cin + c] : 0.f;
  }
  __syncthreads();
  #pragma unroll
  for (int i=0;i<32;i+=8){
    int c = c0+ty+i, r = r0+tx;
    if (c < Cpad) out[(size_t)c*R + r] = f2bf(t[tx][ty+i]);
  }
}

// ---------------- bf16 MFMA GEMM: C[M,Ntrue] (+)= A[M,K] @ Bt[N,K]^T -----------
template<int ACCUM>
__global__ __launch_bounds__(256,2) void gemm_bf16(const unsigned short* __restrict__ A,
    const unsigned short* __restrict__ Bt, float* __restrict__ C,
    int Ntrue, int K, int ldc){
  __shared__ alignas(16) unsigned short As[128*32];
  __shared__ alignas(16) unsigned short Bs[128*32];
  int tid = threadIdx.x;
  int wave = tid >> 6, lane = tid & 63;
  int mBase = blockIdx.y*128, nBase = blockIdx.x*128;
  const size_t K2 = (size_t)K*2;
  int o0 = wave*1024 + lane*16;
  int o1 = o0 + 4096;
  const char* Ag0 = (const char*)A + (size_t)(mBase + (o0>>6))*K2 + (o0&63);
  const char* Ag1 = (const char*)A + (size_t)(mBase + (o1>>6))*K2 + (o1&63);
  const char* Bg0 = (const char*)Bt + (size_t)(nBase + (o0>>6))*K2 + (o0&63);
  const char* Bg1 = (const char*)Bt + (size_t)(nBase + (o1>>6))*K2 + (o1&63);
  char* AsW = (char*)As + wave*1024;
  char* BsW = (char*)Bs + wave*1024;

  int wm = (wave>>1)*64, wn = (wave&1)*64;
  int ln = lane & 15, quad = lane >> 4;

  f32x4 acc[4][4];
  #pragma unroll
  for (int i=0;i<4;i++)
    #pragma unroll
    for (int j=0;j<4;j++) acc[i][j] = (f32x4){0.f,0.f,0.f,0.f};

  for (int k0=0; k0<K; k0+=32){
    size_t kb = (size_t)k0*2;
    __syncthreads();
    load_lds16(Ag0 + kb, AsW);
    load_lds16(Ag1 + kb, AsW + 4096);
    load_lds16(Bg0 + kb, BsW);
    load_lds16(Bg1 + kb, BsW + 4096);
    __syncthreads();
    bf16x8 a[4], b[4];
    #pragma unroll
    for (int mt=0;mt<4;mt++)
      a[mt] = *(const bf16x8*)((const char*)As + (size_t)(wm+mt*16+ln)*64 + quad*16);
    #pragma unroll
    for (int nt=0;nt<4;nt++)
      b[nt] = *(const bf16x8*)((const char*)Bs + (size_t)(wn+nt*16+ln)*64 + quad*16);
    #pragma unroll
    for (int mt=0;mt<4;mt++)
      #pragma unroll
      for (int nt=0;nt<4;nt++)
        acc[mt][nt] = __builtin_amdgcn_mfma_f32_16x16x32_bf16(a[mt], b[nt], acc[mt][nt], 0,0,0);
  }

  #pragma unroll
  for (int mt=0;mt<4;mt++){
    #pragma unroll
    for (int nt=0;nt<4;nt++){
      int col = nBase + wn + nt*16 + ln;
      int row0 = mBase + wm + mt*16 + quad*4;
      if (col < Ntrue){
        #pragma unroll
        for (int r=0;r<4;r++){
          float* p = C + (size_t)(row0+r)*ldc + col;
          float v = acc[mt][nt][r];
          if (ACCUM) v += *p;
          *p = v;
        }
      }
    }
  }
}

// ---------------- dt cumsum ----------------
__global__ __launch_bounds__(256) void dt_scan(const float* __restrict__ zx,
    const float* __restrict__ dtb, const float* __restrict__ alog,
    float* __restrict__ dtt, float* __restrict__ acs){
  int b = blockIdx.x / NH, h = blockIdx.x % NH;
  int tid = threadIdx.x;
  float negA = -expf(alog[h]);
  float bias = dtb[h];
  __shared__ float sc[256];
  for (int c=0;c<NCH;c++){
    int l = c*CHUNKC + tid;
    float xv = zx[((size_t)(b*SEQ+l))*PDIM + (DI+CDIM) + h] + bias;
    float dt = softplusf_(xv);
    float v = dt*negA;
    sc[tid]=v; __syncthreads();
    #pragma unroll
    for (int off=1; off<256; off<<=1){
      float t = (tid>=off)? sc[tid-off]:0.f;
      __syncthreads();
      v += t; sc[tid]=v;
      __syncthreads();
    }
    dtt[(b*NH+h)*SEQ + l] = dt;
    acs[(b*NH+h)*SEQ + l] = v;
  }
}

// ---------------- depthwise causal conv (K=4) + SiLU ------------
__global__ __launch_bounds__(256) void dwconv(const float* __restrict__ zx,
    const float* __restrict__ w, const float* __restrict__ bias,
    float* __restrict__ out){
  int idx = blockIdx.x*256+threadIdx.x;
  if (idx >= BATCH*SEQ*CDIM) return;
  int c = idx % CDIM;
  int l = (idx/CDIM) % SEQ;
  int b = idx / (CDIM*SEQ);
  float s = bias[c];
  const float* col = zx + (size_t)(b*SEQ)*PDIM + DI + c;
  #pragma unroll
  for (int k=0;k<4;k++){
    int li = l-3+k;
    if (li>=0) s += w[c*4+k]*col[(size_t)li*PDIM];
  }
  out[idx] = siluf_(s);
}

// ---------------- SSD: chunk states via MFMA -----------------------------------
// block = (b,c,h). states[p=64][n=128] = sum_j Xd[j,p]*fold_j * B[j,n], K=256.
constexpr int XF_S  = 68;   // floats: fp32 staging rows (64 cols + pad)
constexpr int XDT_S = 72;   // shorts: transposed rows (64 cols + pad), 144B = 16B-aligned
constexpr int BF_S  = 132;  // floats: B staging rows (128 cols + pad), 528B = 16B-aligned
constexpr int BT_S  = 72;   // shorts: B^T rows (64 cols + pad)

__global__ __launch_bounds__(256) void ssd_states_mfma(const float* __restrict__ xbc,
    const float* __restrict__ dtt, const float* __restrict__ acs,
    float* __restrict__ states){
  int blk = blockIdx.x;
  int h = blk % NH, c = (blk/NH) % NCH, b = blk/(NH*NCH);
  int tid = threadIdx.x, wave = tid>>6, lane = tid&63, ln = lane&15, quad = lane>>4;

  __shared__ float ac[CHUNKC];
  __shared__ float fold[CHUNKC];
  __shared__ alignas(16) float Xf[64*XF_S];            // 17.4 KB
  __shared__ alignas(16) unsigned short XdT[64*XDT_S]; //  9.2 KB
  __shared__ alignas(16) float Bf[64*BF_S];            // 33.8 KB
  __shared__ alignas(16) unsigned short BT[128*BT_S];  // 18.4 KB

  int bh = b*NH + h;
  size_t rowbase = (size_t)(b*SEQ + c*CHUNKC);

  ac[tid] = acs[(size_t)bh*SEQ + c*CHUNKC + tid];
  __syncthreads();
  float aclast = ac[CHUNKC-1];
  fold[tid] = dtt[(size_t)bh*SEQ + c*CHUNKC + tid] * expf(aclast - ac[tid]);

  f32x4 acc[8];
  #pragma unroll
  for (int nt=0;nt<8;nt++) acc[nt] = (f32x4){0.f,0.f,0.f,0.f};

  for (int jt=0; jt<4; jt++){
    __syncthreads();
    // stage Xd*fold fp32 (rows j 0..63, cols p 0..63)
    for (int idx=tid; idx<1024; idx+=256){
      int jl = idx>>4, pq = idx&15;
      float f = fold[jt*64 + jl];
      float4 v = *(const float4*)(xbc + (rowbase + jt*64 + jl)*CDIM + h*HD + pq*4);
      v.x*=f; v.y*=f; v.z*=f; v.w*=f;
      *(float4*)&Xf[jl*XF_S + pq*4] = v;
    }
    // stage B fp32 (rows j 0..63, cols n 0..127)
    for (int idx=tid; idx<2048; idx+=256){
      int jl = idx>>5, nq = idx&31;
      *(float4*)&Bf[jl*BF_S + nq*4] =
          *(const float4*)(xbc + (rowbase + jt*64 + jl)*CDIM + DI + nq*4);
    }
    __syncthreads();
    // transpose Xf -> XdT (row p, col j)
    {
      int p = tid>>2, jq = tid&3;
      #pragma unroll
      for (int ji=0; ji<16; ji++){
        int j = jq*16+ji;
        XdT[p*XDT_S + j] = f2bf(Xf[j*XF_S + p]);
      }
    }
    // transpose Bf -> BT (row n, col j)
    {
      int n = tid>>1, jh = tid&1;
      #pragma unroll
      for (int ji=0; ji<32; ji++){
        int j = jh*32+ji;
        BT[n*BT_S + j] = f2bf(Bf[j*BF_S + n]);
      }
    }
    __syncthreads();
    bf16x8 aX[2];
    #pragma unroll
    for (int kq=0;kq<2;kq++)
      aX[kq] = *(const bf16x8*)&XdT[(wave*16+ln)*XDT_S + kq*32 + quad*8];
    #pragma unroll
    for (int nt=0;nt<8;nt++){
      #pragma unroll
      for (int kq=0;kq<2;kq++){
        bf16x8 bB = *(const bf16x8*)&BT[(nt*16+ln)*BT_S + kq*32 + quad*8];
        acc[nt] = __builtin_amdgcn_mfma_f32_16x16x32_bf16(aX[kq], bB, acc[nt], 0,0,0);
      }
    }
  }

  float* sp = states + (((size_t)(b*NCH+c)*NH + h) << 13);
  #pragma unroll
  for (int nt=0;nt<8;nt++){
    #pragma unroll
    for (int r=0;r<4;r++){
      sp[(size_t)(wave*16 + quad*4 + r)*DSTATE + nt*16 + ln] = acc[nt][r];
    }
  }
}

// ---------------- inter-chunk scan ----------------
__global__ __launch_bounds__(256) void ssd_scan(const float* __restrict__ states,
    const float* __restrict__ acs, float* __restrict__ prev){
  int idx = blockIdx.x*256+threadIdx.x;
  if (idx >= BATCH*NH*HD*DSTATE) return;
  int pn = idx & 8191;
  int bh = idx >> 13;
  int h = bh % NH, b = bh / NH;
  float carry = 0.f;
  #pragma unroll
  for (int c=0;c<NCH;c++){
    size_t o = (((size_t)(b*NCH+c)*NH + h) << 13) + pn;
    prev[o] = carry;
    float dec = expf(acs[(b*NH+h)*SEQ + c*CHUNKC + CHUNKC-1]);
    carry = carry*dec + states[o];
  }
}

// ---------------- SSD diag + off-diag + skip via MFMA --------------------------
constexpr int CW_S  = 136;  // shorts
constexpr int SB_S  = 72;   // shorts

__global__ __launch_bounds__(256,2) void ssd_diag_mfma(
    const float* __restrict__ xbc, const float* __restrict__ dtt,
    const float* __restrict__ acs, const float* __restrict__ prev,
    const float* __restrict__ dskip, float* __restrict__ Y){
  int blk = blockIdx.x;
  int t = blk & 3;
  int r0 = blk >> 2;
  int h = r0 % NH;  r0 /= NH;
  int c = r0 % NCH;
  int b = r0 / NCH;

  int tid = threadIdx.x;
  int wave = tid>>6, lane = tid&63, ln = lane&15, quad = lane>>4;

  __shared__ float ac[CHUNKC];
  __shared__ alignas(16) unsigned short Cw[64*CW_S];
  __shared__ alignas(16) unsigned short Pv[64*CW_S];
  __shared__ alignas(16) unsigned short XdT[64*XDT_S];
  __shared__ alignas(16) unsigned short Sb[4][16*SB_S];
  __shared__ alignas(16) char uBX[64*CW_S*2];
  unsigned short* Bt = (unsigned short*)uBX;
  float* Xf = (float*)uBX;

  const int bh = b*NH + h;
  const size_t rowbase = (size_t)(b*SEQ + c*CHUNKC);

  ac[tid] = acs[(size_t)bh*SEQ + c*CHUNKC + tid];

  const float* pvsrc = prev + (((size_t)(b*NCH+c)*NH + h) << 13);
  for (int idx=tid; idx<2048; idx+=256){
    int row = idx>>5, nq = idx&31;
    float4 v = *(const float4*)(xbc + (rowbase + t*64 + row)*CDIM + DI + DSTATE + nq*4);
    ushort4 u; u.x=f2bf(v.x); u.y=f2bf(v.y); u.z=f2bf(v.z); u.w=f2bf(v.w);
    *(ushort4*)&Cw[row*CW_S + nq*4] = u;
    float4 w = *(const float4*)(pvsrc + (size_t)row*DSTATE + nq*4);
    ushort4 uw; uw.x=f2bf(w.x); uw.y=f2bf(w.y); uw.z=f2bf(w.z); uw.w=f2bf(w.w);
    *(ushort4*)&Pv[row*CW_S + nq*4] = uw;
  }
  __syncthreads();

  bf16x8 aC[4];
  #pragma unroll
  for (int kq=0;kq<4;kq++)
    aC[kq] = *(const bf16x8*)&Cw[(wave*16+ln)*CW_S + kq*32 + quad*8];

  f32x4 yacc[4];
  #pragma unroll
  for (int ps=0;ps<4;ps++) yacc[ps] = (f32x4){0.f,0.f,0.f,0.f};

  for (int jt=0; jt<=t; jt++){
    __syncthreads();
    for (int idx=tid; idx<1024; idx+=256){
      int jl = idx>>4, pq = idx&15;
      float d = dtt[(size_t)bh*SEQ + c*CHUNKC + jt*64 + jl];
      float4 v = *(const float4*)(xbc + (rowbase + jt*64 + jl)*CDIM + h*HD + pq*4);
      v.x*=d; v.y*=d; v.z*=d; v.w*=d;
      *(float4*)&Xf[jl*XF_S + pq*4] = v;
    }
    __syncthreads();
    {
      int p = tid>>2, jq = tid&3;
      #pragma unroll
      for (int ji=0; ji<16; ji++){
        int j = jq*16+ji;
        XdT[p*XDT_S + j] = f2bf(Xf[j*XF_S + p]);
      }
    }
    __syncthreads();
    for (int idx=tid; idx<2048; idx+=256){
      int row = idx>>5, nq = idx&31;
      float4 v = *(const float4*)(xbc + (rowbase + jt*64 + row)*CDIM + DI + nq*4);
      ushort4 u; u.x=f2bf(v.x); u.y=f2bf(v.y); u.z=f2bf(v.z); u.w=f2bf(v.w);
      *(ushort4*)&Bt[row*CW_S + nq*4] = u;
    }
    __syncthreads();

    #pragma unroll
    for (int js=0; js<4; js++){
      f32x4 s = (f32x4){0.f,0.f,0.f,0.f};
      #pragma unroll
      for (int kq=0;kq<4;kq++){
        bf16x8 bB = *(const bf16x8*)&Bt[(js*16+ln)*CW_S + kq*32 + quad*8];
        s = __builtin_amdgcn_mfma_f32_16x16x32_bf16(aC[kq], bB, s, 0,0,0);
      }
      int jc = jt*64 + js*16 + ln;
      #pragma unroll
      for (int r=0;r<4;r++){
        int icl = t*64 + wave*16 + quad*4 + r;
        float d = (jc<=icl) ? (ac[icl]-ac[jc]) : -1e30f;
        Sb[wave][(quad*4+r)*SB_S + js*16 + ln] = f2bf(expf(d)*s[r]);
      }
    }
    bf16x8 aS[2];
    #pragma unroll
    for (int kq=0;kq<2;kq++)
      aS[kq] = *(const bf16x8*)&Sb[wave][ln*SB_S + kq*32 + quad*8];
    #pragma unroll
    for (int ps=0;ps<4;ps++){
      #pragma unroll
      for (int kq=0;kq<2;kq++){
        bf16x8 bX = *(const bf16x8*)&XdT[(ps*16+ln)*XDT_S + kq*32 + quad*8];
        yacc[ps] = __builtin_amdgcn_mfma_f32_16x16x32_bf16(aS[kq], bX, yacc[ps], 0,0,0);
      }
    }
  }

  f32x4 oacc[4];
  #pragma unroll
  for (int ps=0;ps<4;ps++) oacc[ps] = (f32x4){0.f,0.f,0.f,0.f};
  #pragma unroll
  for (int ps=0;ps<4;ps++){
    #pragma unroll
    for (int kq=0;kq<4;kq++){
      bf16x8 bP = *(const bf16x8*)&Pv[(ps*16+ln)*CW_S + kq*32 + quad*8];
      oacc[ps] = __builtin_amdgcn_mfma_f32_16x16x32_bf16(aC[kq], bP, oacc[ps], 0,0,0);
    }
  }

  float dsk = dskip[h];
  #pragma unroll
  for (int r=0;r<4;r++){
    int icl = t*64 + wave*16 + quad*4 + r;
    float ei = expf(ac[icl]);
    size_t l = rowbase + icl;
    #pragma unroll
    for (int ps=0;ps<4;ps++){
      int p = ps*16 + ln;
      float xraw = xbc[l*CDIM + h*HD + p];
      Y[l*DI + h*HD + p] = yacc[ps][r] + ei*oacc[ps][r] + dsk*xraw;
    }
  }
}

// ---------------- gate (silu(z)) + rmsnorm over 1536 -> bf16 ------------
__global__ __launch_bounds__(256) void gate_rms(const float* __restrict__ zx,
    const float* __restrict__ gnw, const float* __restrict__ Y,
    unsigned short* __restrict__ Yb){
  int row = blockIdx.x;
  const float* z = zx + (size_t)row*PDIM;
  const float* y = Y + (size_t)row*DI;
  float vals[6]; float ss=0.f;
  #pragma unroll
  for (int t=0;t<6;t++){
    int d = threadIdx.x + t*256;
    float v = y[d]*siluf_(z[d]);
    vals[t]=v; ss+=v*v;
  }
  __shared__ float red[4];
  float tot = block_sum_256(ss, red);
  float sc = rsqrtf(tot*(1.f/DI)+EPSF);
  #pragma unroll
  for (int t=0;t<6;t++){
    int d = threadIdx.x + t*256;
    Yb[(size_t)row*DI + d] = f2bf(vals[t]*sc*gnw[d]);
  }
}

// ---------------- final pooling + head -----------------------------------------
__global__ __launch_bounds__(256) void mean_pool(const float* __restrict__ hn,
    float* __restrict__ pooled){
  int idx = blockIdx.x*256+threadIdx.x;
  if (idx >= BATCH*DM) return;
  int b = idx / DM, d = idx % DM;
  float s = 0.f;
  for (int l=0;l<SEQ;l++) s += hn[((size_t)(b*SEQ+l))*DM + d];
  pooled[idx] = s * (1.f/SEQ);
}

__global__ __launch_bounds__(512) void head_k(const float* __restrict__ pooled,
    const float* __restrict__ w1, const float* __restrict__ b1,
    const float* __restrict__ g, const float* __restrict__ bb,
    const float* __restrict__ mn, const float* __restrict__ vr,
    const float* __restrict__ w2, const float* __restrict__ b2,
    float* __restrict__ out){
  int b = blockIdx.x;
  int j = threadIdx.x;
  __shared__ float f[512];
  __shared__ float pl[DM];
  for (int t=j; t<DM; t+=512) pl[t] = pooled[b*DM+t];
  __syncthreads();
  float s = b1[j];
  for (int k=0;k<DM;k++) s += pl[k]*w1[k*512+j];
  s = (s-mn[j])*(g[j]*rsqrtf(vr[j]+EPSF)) + bb[j];
  f[j] = fmaxf(s,0.f);
  __syncthreads();
  if (j < 27){
    float o = b2[j];
    for (int k=0;k<512;k++) o += f[k]*w2[k*27+j];
    out[b*27+j] = o;
  }
}

extern "C" void kernel_launch(void* const* d_in, const int* in_sizes, int n_in,
                              void* d_out, int out_size, void* d_ws, size_t ws_size,
                              hipStream_t stream){
  const float* x      = (const float*)d_in[0];
  const float* c1_w   = (const float*)d_in[1];
  const float* c1_b   = (const float*)d_in[2];
  const float* bn1_g  = (const float*)d_in[3];
  const float* bn1_b  = (const float*)d_in[4];
  const float* bn1_m  = (const float*)d_in[5];
  const float* bn1_v  = (const float*)d_in[6];
  const float* c2_w   = (const float*)d_in[7];
  const float* c2_b   = (const float*)d_in[8];
  const float* bn2_g  = (const float*)d_in[9];
  const float* bn2_b  = (const float*)d_in[10];
  const float* bn2_m  = (const float*)d_in[11];
  const float* bn2_v  = (const float*)d_in[12];
  const float* c3_w   = (const float*)d_in[13];
  const float* c3_b   = (const float*)d_in[14];
  const float* bn3_g  = (const float*)d_in[15];
  const float* bn3_b  = (const float*)d_in[16];
  const float* bn3_m  = (const float*)d_in[17];
  const float* bn3_v  = (const float*)d_in[18];
  const float* ln_w   = (const float*)d_in[19];
  const float* inpw   = (const float*)d_in[20];
  const float* convw  = (const float*)d_in[21];
  const float* convb  = (const float*)d_in[22];
  const float* dtb    = (const float*)d_in[23];
  const float* alog   = (const float*)d_in[24];
  const float* dskip  = (const float*)d_in[25];
  const float* gnw    = (const float*)d_in[26];
  const float* outw   = (const float*)d_in[27];
  const float* normfw = (const float*)d_in[28];
  const float* fc1w   = (const float*)d_in[29];
  const float* fc1b   = (const float*)d_in[30];
  const float* bncg   = (const float*)d_in[31];
  const float* bncb   = (const float*)d_in[32];
  const float* bncm   = (const float*)d_in[33];
  const float* bncv   = (const float*)d_in[34];
  const float* fc2w   = (const float*)d_in[35];
  const float* fc2b   = (const float*)d_in[36];
  (void)in_sizes; (void)n_in; (void)out_size; (void)ws_size;

  char* ws = (char*)d_ws;
  size_t off = 0;
  auto alloc = [&](size_t bytes){
    char* p = ws + off;
    off += (bytes + 255) & ~(size_t)255;
    return (void*)p;
  };
  float* h1  = (float*)alloc((size_t)BATCH*192*LS1*4);
  float* h2  = (float*)alloc((size_t)BATCH*384*LS2*4);
  float* h   = (float*)alloc((size_t)BATCH*SEQ*DM*4);
  float* hn  = (float*)alloc((size_t)BATCH*SEQ*DM*4);
  float* zx  = (float*)alloc((size_t)BATCH*SEQ*PDIM*4);
  float* xbc = (float*)alloc((size_t)BATCH*SEQ*CDIM*4);
  float* dtt = (float*)alloc((size_t)BATCH*NH*SEQ*4);
  float* acs = (float*)alloc((size_t)BATCH*NH*SEQ*4);
  float* st  = (float*)alloc((size_t)BATCH*NCH*NH*HD*DSTATE*4);
  float* pv  = (float*)alloc((size_t)BATCH*NCH*NH*HD*DSTATE*4);
  float* Y   = (float*)alloc((size_t)BATCH*SEQ*DI*4);
  float* pooled = (float*)alloc((size_t)BATCH*DM*4);
  unsigned short* hnb   = (unsigned short*)alloc((size_t)BATCH*SEQ*DM*2);
  unsigned short* Yb    = (unsigned short*)alloc((size_t)BATCH*SEQ*DI*2);
  unsigned short* wtin  = (unsigned short*)alloc((size_t)PPAD*DM*2);
  unsigned short* wtout = (unsigned short*)alloc((size_t)DM*DI*2);

  conv_stem1<<<(BATCH*192*LS1+255)/256,256,0,stream>>>(x, c1_w,c1_b, bn1_g,bn1_b,bn1_m,bn1_v, h1);
  conv_stem2<<<(BATCH*384*LS2+255)/256,256,0,stream>>>(h1, c2_w,c2_b, bn2_g,bn2_b,bn2_m,bn2_v, h2);
  conv_stem3<<<BATCH*768,256,0,stream>>>(h2, c3_w,c3_b, bn3_g,bn3_b,bn3_m,bn3_v, h);

  const int M = BATCH*SEQ;  // 2048
  for (int l=0; l<NLAYER; l++){
    transpose_cvt<<<dim3(PPAD/32, DM/32),256,0,stream>>>(inpw + (size_t)l*DM*PDIM, wtin, DM, PDIM, PPAD);
    transpose_cvt<<<dim3(DM/32, DI/32),256,0,stream>>>(outw + (size_t)l*DI*DM, wtout, DI, DM, DM);

    rmsnorm768<1><<<M,256,0,stream>>>(h, ln_w + (size_t)l*DM, nullptr, hnb);
    gemm_bf16<0><<<dim3(PPAD/128, M/128),256,0,stream>>>(hnb, wtin, zx, PDIM, DM, PDIM);
    dt_scan<<<BATCH*NH,256,0,stream>>>(zx, dtb + l*NH, alog + l*NH, dtt, acs);
    dwconv<<<(BATCH*SEQ*CDIM+255)/256,256,0,stream>>>(zx, convw + (size_t)l*CDIM*4, convb + (size_t)l*CDIM, xbc);
    ssd_states_mfma<<<BATCH*NCH*NH,256,0,stream>>>(xbc, dtt, acs, st);
    ssd_scan<<<(BATCH*NH*HD*DSTATE+255)/256,256,0,stream>>>(st, acs, pv);
    ssd_diag_mfma<<<BATCH*NCH*NH*4,256,0,stream>>>(xbc, dtt, acs, pv, dskip + l*NH, Y);
    gate_rms<<<M,256,0,stream>>>(zx, gnw + (size_t)l*DI, Y, Yb);
    gemm_bf16<1><<<dim3(DM/128, M/128),256,0,stream>>>(Yb, wtout, h, DM, DI, DM);
  }

  rmsnorm768<0><<<M,256,0,stream>>>(h, normfw, hn, nullptr);
  mean_pool<<<(BATCH*DM+255)/256,256,0,stream>>>(hn, pooled);
  head_k<<<BATCH,512,0,stream>>>(pooled, fc1w, fc1b, bncg,bncb,bncm,bncv, fc2w, fc2b, (float*)d_out);
}

// Round 5
// 4502.828 us; speedup vs baseline: 6.1649x; 1.3303x over previous
//
#include <hip/hip_runtime.h>
#include <math.h>

#define DEV __device__ __forceinline__

constexpr int BATCH = 2;
constexpr int L0 = 4096;
constexpr int LS1 = 2048;
constexpr int LS2 = 1024;
constexpr int SEQ = 1024;
constexpr int DM = 768;
constexpr int NH = 24;
constexpr int HD = 64;
constexpr int DI = 1536;
constexpr int DSTATE = 128;
constexpr int CDIM = 1792;   // DI + 2*DSTATE
constexpr int PDIM = 3352;   // 2*DI + 2*DSTATE + NH
constexpr int PPAD = 3456;   // PDIM padded to 27*128
constexpr int CHUNKC = 256;
constexpr int NCH = 4;
constexpr int NLAYER = 24;
constexpr float EPSF = 1e-5f;

typedef short bf16x8 __attribute__((ext_vector_type(8)));
typedef float f32x4 __attribute__((ext_vector_type(4)));

DEV float sigmoidf_(float x){ return 1.f/(1.f+expf(-x)); }
DEV float siluf_(float x){ return x*sigmoidf_(x); }
DEV float geluf_(float x){ return 0.5f*x*(1.f+erff(x*0.70710678118654752440f)); }
DEV float softplusf_(float x){ return fmaxf(x,0.f) + log1pf(expf(-fabsf(x))); }

DEV unsigned short f2bf(float x){
  union { float f; unsigned int u; } v; v.f = x;
  unsigned int u = v.u;
  unsigned int r = (u + 0x7fffu + ((u>>16)&1u)) >> 16;
  return (unsigned short)r;
}
DEV float bf2f(unsigned short u){
  union { unsigned int u; float f; } v; v.u = ((unsigned int)u)<<16; return v.f;
}

DEV void load_lds16(const void* g, void* l){
  __builtin_amdgcn_global_load_lds(
      (const __attribute__((address_space(1))) unsigned int*)g,
      (__attribute__((address_space(3))) unsigned int*)l,
      16, 0, 0);
}

DEV float block_sum_256(float v, float* red4){
  #pragma unroll
  for (int o=32;o>0;o>>=1) v += __shfl_down(v,o,64);
  int tid = threadIdx.x;
  __syncthreads();
  if ((tid&63)==0) red4[tid>>6]=v;
  __syncthreads();
  return red4[0]+red4[1]+red4[2]+red4[3];
}

// ---------------- stem ----------------
__global__ __launch_bounds__(256) void conv_stem1(const float* __restrict__ x,
    const float* __restrict__ w, const float* __restrict__ bias,
    const float* __restrict__ g, const float* __restrict__ bb,
    const float* __restrict__ mn, const float* __restrict__ vr,
    float* __restrict__ out){
  int idx = blockIdx.x*256+threadIdx.x;
  if (idx >= BATCH*192*LS1) return;
  int lo = idx & (LS1-1);
  int co = (idx >> 11) % 192;
  int b  = idx / (192*LS1);
  float s = bias[co];
  const float* wr = w + co*60;
  #pragma unroll
  for (int ci=0; ci<12; ci++){
    const float* xr = x + ((size_t)(b*12+ci))*L0;
    #pragma unroll
    for (int k=0;k<5;k++){
      int li = lo*2 + k - 2;
      if (li>=0 && li<L0) s += wr[ci*5+k]*xr[li];
    }
  }
  s = geluf_(s);
  s = (s-mn[co])*(g[co]*rsqrtf(vr[co]+EPSF)) + bb[co];
  out[idx] = s;
}

__global__ __launch_bounds__(256) void conv_stem2(const float* __restrict__ x,
    const float* __restrict__ w, const float* __restrict__ bias,
    const float* __restrict__ g, const float* __restrict__ bb,
    const float* __restrict__ mn, const float* __restrict__ vr,
    float* __restrict__ out){
  int idx = blockIdx.x*256+threadIdx.x;
  if (idx >= BATCH*384*LS2) return;
  int lo = idx & (LS2-1);
  int co = (idx >> 10) % 384;
  int b  = idx / (384*LS2);
  float s = bias[co];
  const float* wr = w + co*(192*3);
  const float* xb = x + (size_t)b*192*LS1;
  for (int ci=0; ci<192; ci++){
    const float* base = xb + ci*LS1;
    int l2 = lo*2;
    s += wr[ci*3+1]*base[l2];
    s += wr[ci*3+2]*base[l2+1];
    if (lo>0) s += wr[ci*3]*base[l2-1];
  }
  s = geluf_(s);
  s = (s-mn[co])*(g[co]*rsqrtf(vr[co]+EPSF)) + bb[co];
  out[idx] = s;
}

__global__ __launch_bounds__(256) void conv_stem3(const float* __restrict__ x,
    const float* __restrict__ w, const float* __restrict__ bias,
    const float* __restrict__ g, const float* __restrict__ bb,
    const float* __restrict__ mn, const float* __restrict__ vr,
    float* __restrict__ h){
  int co = blockIdx.x % 768;
  int b  = blockIdx.x / 768;
  __shared__ float wsh[384*3];
  for (int t=threadIdx.x; t<384*3; t+=256) wsh[t] = w[(size_t)co*1152 + t];
  __syncthreads();
  const float* xb = x + (size_t)b*384*LS2;
  float scale = g[co]*rsqrtf(vr[co]+EPSF);
  float bnb = bb[co], bnm = mn[co], bs0 = bias[co];
  #pragma unroll
  for (int s=0;s<4;s++){
    int lo = s*256 + threadIdx.x;
    int offm = (lo>0)? -1 : 0;        float mm = (lo>0)? 1.f : 0.f;
    int offp = (lo<LS2-1)? 1 : 0;     float mp = (lo<LS2-1)? 1.f : 0.f;
    float acc = bs0;
    for (int ci=0; ci<384; ci++){
      const float* xr = xb + ci*LS2 + lo;
      float w0=wsh[ci*3+0], w1=wsh[ci*3+1], w2=wsh[ci*3+2];
      acc += w1*xr[0];
      acc += mm*w0*xr[offm];
      acc += mp*w2*xr[offp];
    }
    acc = geluf_(acc);
    acc = (acc-bnm)*scale + bnb;
    h[((size_t)(b*SEQ+lo))*DM + co] = acc;
  }
}

// ---------------- rmsnorm (D=768) ----------------
template<int BF>
__global__ __launch_bounds__(256) void rmsnorm768(const float* __restrict__ in,
    const float* __restrict__ w, float* __restrict__ outf, unsigned short* __restrict__ outb){
  int row = blockIdx.x;
  const float* p = in + (size_t)row*DM;
  float v0[3]; float ss=0.f;
  #pragma unroll
  for (int t=0;t<3;t++){ float q = p[threadIdx.x + t*256]; v0[t]=q; ss+=q*q; }
  __shared__ float red[4];
  float tot = block_sum_256(ss, red);
  float sc = rsqrtf(tot*(1.f/DM) + EPSF);
  #pragma unroll
  for (int t=0;t<3;t++){
    int d = threadIdx.x + t*256;
    float o = v0[t]*sc*w[d];
    if (BF) outb[(size_t)row*DM + d] = f2bf(o);
    else    outf[(size_t)row*DM + d] = o;
  }
}

// ---------------- transpose + fp32->bf16 convert: in (R,Cin) -> out (Cpad,R) ---
__global__ __launch_bounds__(256) void transpose_cvt(const float* __restrict__ in,
    unsigned short* __restrict__ out, int R, int Cin, int Cpad){
  __shared__ float t[32][33];
  int c0 = blockIdx.x*32, r0 = blockIdx.y*32;
  int tx = threadIdx.x & 31, ty = threadIdx.x >> 5;
  #pragma unroll
  for (int i=0;i<32;i+=8){
    int r = r0+ty+i, c = c0+tx;
    t[ty+i][tx] = (c<Cin) ? in[(size_t)r*Cin + c] : 0.f;
  }
  __syncthreads();
  #pragma unroll
  for (int i=0;i<32;i+=8){
    int c = c0+ty+i, r = r0+tx;
    if (c < Cpad) out[(size_t)c*R + r] = f2bf(t[tx][ty+i]);
  }
}

// ---------------- bf16 MFMA GEMM 128x128: MODE 0=f32 store, 2=bf16 store -------
template<int MODE>
__global__ __launch_bounds__(256,2) void gemm_bf16(const unsigned short* __restrict__ A,
    const unsigned short* __restrict__ Bt, float* __restrict__ Cf,
    unsigned short* __restrict__ Cb, int Ntrue, int K, int ldc){
  __shared__ alignas(16) unsigned short As[128*32];
  __shared__ alignas(16) unsigned short Bs[128*32];
  int tid = threadIdx.x;
  int wave = tid >> 6, lane = tid & 63;
  int mBase = blockIdx.y*128, nBase = blockIdx.x*128;
  const size_t K2 = (size_t)K*2;
  int o0 = wave*1024 + lane*16;
  int o1 = o0 + 4096;
  const char* Ag0 = (const char*)A + (size_t)(mBase + (o0>>6))*K2 + (o0&63);
  const char* Ag1 = (const char*)A + (size_t)(mBase + (o1>>6))*K2 + (o1&63);
  const char* Bg0 = (const char*)Bt + (size_t)(nBase + (o0>>6))*K2 + (o0&63);
  const char* Bg1 = (const char*)Bt + (size_t)(nBase + (o1>>6))*K2 + (o1&63);
  char* AsW = (char*)As + wave*1024;
  char* BsW = (char*)Bs + wave*1024;

  int wm = (wave>>1)*64, wn = (wave&1)*64;
  int ln = lane & 15, quad = lane >> 4;

  f32x4 acc[4][4];
  #pragma unroll
  for (int i=0;i<4;i++)
    #pragma unroll
    for (int j=0;j<4;j++) acc[i][j] = (f32x4){0.f,0.f,0.f,0.f};

  for (int k0=0; k0<K; k0+=32){
    size_t kb = (size_t)k0*2;
    __syncthreads();
    load_lds16(Ag0 + kb, AsW);
    load_lds16(Ag1 + kb, AsW + 4096);
    load_lds16(Bg0 + kb, BsW);
    load_lds16(Bg1 + kb, BsW + 4096);
    __syncthreads();
    bf16x8 a[4], b[4];
    #pragma unroll
    for (int mt=0;mt<4;mt++)
      a[mt] = *(const bf16x8*)((const char*)As + (size_t)(wm+mt*16+ln)*64 + quad*16);
    #pragma unroll
    for (int nt=0;nt<4;nt++)
      b[nt] = *(const bf16x8*)((const char*)Bs + (size_t)(wn+nt*16+ln)*64 + quad*16);
    #pragma unroll
    for (int mt=0;mt<4;mt++)
      #pragma unroll
      for (int nt=0;nt<4;nt++)
        acc[mt][nt] = __builtin_amdgcn_mfma_f32_16x16x32_bf16(a[mt], b[nt], acc[mt][nt], 0,0,0);
  }

  #pragma unroll
  for (int mt=0;mt<4;mt++){
    #pragma unroll
    for (int nt=0;nt<4;nt++){
      int col = nBase + wn + nt*16 + ln;
      int row0 = mBase + wm + mt*16 + quad*4;
      if (col < Ntrue){
        #pragma unroll
        for (int r=0;r<4;r++){
          float v = acc[mt][nt][r];
          if (MODE==2) Cb[(size_t)(row0+r)*ldc + col] = f2bf(v);
          else         Cf[(size_t)(row0+r)*ldc + col] = v;
        }
      }
    }
  }
}

// ---------------- bf16 MFMA GEMM 64x64 tile, fp32 accumulate into C ------------
// grid (N/64, M/64). 4 waves: wave w -> rows w*16..w*16+15, all 64 cols. BK=64.
__global__ __launch_bounds__(256,2) void gemm_acc64(const unsigned short* __restrict__ A,
    const unsigned short* __restrict__ Bt, float* __restrict__ C, int N, int K){
  __shared__ alignas(16) unsigned short As[64*72];
  __shared__ alignas(16) unsigned short Bs[64*72];
  int tid = threadIdx.x;
  int wave = tid>>6, lane = tid&63, ln = lane&15, quad = lane>>4;
  int mBase = blockIdx.y*64, nBase = blockIdx.x*64;
  int srow = tid>>2, sseg = tid&3;
  const unsigned short* Ag = A + (size_t)(mBase+srow)*K + sseg*8;
  const unsigned short* Bg = Bt + (size_t)(nBase+srow)*K + sseg*8;

  f32x4 acc[4];
  #pragma unroll
  for (int nt=0;nt<4;nt++) acc[nt] = (f32x4){0.f,0.f,0.f,0.f};

  for (int k0=0; k0<K; k0+=64){
    __syncthreads();
    #pragma unroll
    for (int s=0;s<2;s++){
      *(bf16x8*)&As[srow*72 + (sseg+s*4)*8] = *(const bf16x8*)(Ag + k0 + s*32);
      *(bf16x8*)&Bs[srow*72 + (sseg+s*4)*8] = *(const bf16x8*)(Bg + k0 + s*32);
    }
    __syncthreads();
    bf16x8 a[2];
    #pragma unroll
    for (int kq=0;kq<2;kq++)
      a[kq] = *(const bf16x8*)&As[(wave*16+ln)*72 + kq*32 + quad*8];
    #pragma unroll
    for (int nt=0;nt<4;nt++){
      #pragma unroll
      for (int kq=0;kq<2;kq++){
        bf16x8 b = *(const bf16x8*)&Bs[(nt*16+ln)*72 + kq*32 + quad*8];
        acc[nt] = __builtin_amdgcn_mfma_f32_16x16x32_bf16(a[kq], b, acc[nt], 0,0,0);
      }
    }
  }
  #pragma unroll
  for (int nt=0;nt<4;nt++){
    int col = nBase + nt*16 + ln;
    int row0 = mBase + wave*16 + quad*4;
    #pragma unroll
    for (int r=0;r<4;r++){
      float* p = C + (size_t)(row0+r)*N + col;
      *p += acc[nt][r];
    }
  }
}

// ---------------- dt cumsum (parallel over chunks) ----------------
__global__ __launch_bounds__(256) void dt_scan_p(const unsigned short* __restrict__ zxb,
    const float* __restrict__ dtb, const float* __restrict__ alog,
    float* __restrict__ dtt, float* __restrict__ acs){
  int blk = blockIdx.x;
  int c = blk % NCH, h = (blk/NCH) % NH, b = blk/(NCH*NH);
  int tid = threadIdx.x;
  int l = c*CHUNKC + tid;
  float negA = -expf(alog[h]);
  float lg = bf2f(zxb[((size_t)(b*SEQ+l))*PDIM + (DI+CDIM) + h]) + dtb[h];
  float dt = softplusf_(lg);
  float v = dt*negA;
  __shared__ float sc[256];
  sc[tid]=v; __syncthreads();
  #pragma unroll
  for (int off=1; off<256; off<<=1){
    float t = (tid>=off)? sc[tid-off]:0.f;
    __syncthreads();
    v += t; sc[tid]=v;
    __syncthreads();
  }
  dtt[(b*NH+h)*SEQ + l] = dt;
  acs[(b*NH+h)*SEQ + l] = v;
}

// ---------------- depthwise causal conv (K=4) + SiLU, bf16 in/out --------------
__global__ __launch_bounds__(256) void dwconv(const unsigned short* __restrict__ zxb,
    const float* __restrict__ w, const float* __restrict__ bias,
    unsigned short* __restrict__ out){
  int idx = blockIdx.x*256+threadIdx.x;
  if (idx >= BATCH*SEQ*CDIM) return;
  int c = idx % CDIM;
  int l = (idx/CDIM) % SEQ;
  int b = idx / (CDIM*SEQ);
  float s = bias[c];
  const unsigned short* col = zxb + (size_t)(b*SEQ)*PDIM + DI + c;
  #pragma unroll
  for (int k=0;k<4;k++){
    int li = l-3+k;
    if (li>=0) s += w[c*4+k]*bf2f(col[(size_t)li*PDIM]);
  }
  out[idx] = f2bf(siluf_(s));
}

// ---------------- xprep: XdT[bh][p][l]=X*dt, Xdec=X*dt*exp(acLast-ac) ----------
__global__ __launch_bounds__(256) void xprep(const unsigned short* __restrict__ xbcb,
    const float* __restrict__ dtt, const float* __restrict__ acs,
    unsigned short* __restrict__ XdT, unsigned short* __restrict__ Xdec){
  int blk = blockIdx.x;
  int lt = blk & 15, bh = blk >> 4;
  int b = bh / NH, h = bh % NH;
  int tid = threadIdx.x;
  __shared__ alignas(16) unsigned short Xs[64*72];
  __shared__ float dts[64], decs[64];
  int srow = tid>>2, sseg = tid&3;
  const unsigned short* src = xbcb + ((size_t)(b*SEQ) + lt*64 + srow)*CDIM + h*HD;
  #pragma unroll
  for (int s=0;s<2;s++)
    *(bf16x8*)&Xs[srow*72 + (sseg+s*4)*8] = *(const bf16x8*)(src + (sseg+s*4)*8);
  if (tid < 64){
    int c = lt >> 2;
    float aclast = acs[(size_t)bh*SEQ + c*CHUNKC + CHUNKC-1];
    dts[tid]  = dtt[(size_t)bh*SEQ + lt*64 + tid];
    decs[tid] = expf(aclast - acs[(size_t)bh*SEQ + lt*64 + tid]);
  }
  __syncthreads();
  int p = tid>>2, lq = tid&3;
  unsigned short o1[16], o2[16];
  #pragma unroll
  for (int li=0; li<16; li++){
    int l = lq*16+li;
    float v = bf2f(Xs[l*72 + p]) * dts[l];
    o1[li] = f2bf(v);
    o2[li] = f2bf(v*decs[l]);
  }
  size_t rowo = ((size_t)bh*HD + p)*SEQ + lt*64 + lq*16;
  *(bf16x8*)(XdT + rowo)     = *(bf16x8*)&o1[0];
  *(bf16x8*)(XdT + rowo + 8) = *(bf16x8*)&o1[8];
  *(bf16x8*)(Xdec + rowo)     = *(bf16x8*)&o2[0];
  *(bf16x8*)(Xdec + rowo + 8) = *(bf16x8*)&o2[8];
}

// ---------------- btprep: BT[b][n][l] = B[l][n] ----------------
__global__ __launch_bounds__(256) void btprep(const unsigned short* __restrict__ xbcb,
    unsigned short* __restrict__ BTg){
  int blk = blockIdx.x;
  int nh = blk & 1, lt = (blk>>1) & 15, b = blk >> 5;
  int tid = threadIdx.x;
  __shared__ alignas(16) unsigned short Bs[64*72];
  int srow = tid>>2, sseg = tid&3;
  const unsigned short* src = xbcb + ((size_t)(b*SEQ) + lt*64 + srow)*CDIM + DI + nh*64;
  #pragma unroll
  for (int s=0;s<2;s++)
    *(bf16x8*)&Bs[srow*72 + (sseg+s*4)*8] = *(const bf16x8*)(src + (sseg+s*4)*8);
  __syncthreads();
  int n = tid>>2, lq = tid&3;
  unsigned short o[16];
  #pragma unroll
  for (int li=0; li<16; li++) o[li] = Bs[(lq*16+li)*72 + n];
  size_t rowo = ((size_t)b*DSTATE + nh*64 + n)*SEQ + lt*64 + lq*16;
  *(bf16x8*)(BTg + rowo)     = *(bf16x8*)&o[0];
  *(bf16x8*)(BTg + rowo + 8) = *(bf16x8*)&o[8];
}

// ---------------- SSD chunk states: D[p=64][n=64] = Xdec[p][:] . BT[n][:]^T ----
// grid (b,c,h,nh) = 384 blocks. K=256 single-shot staging.
__global__ __launch_bounds__(256) void ssd_states2(const unsigned short* __restrict__ Xdec,
    const unsigned short* __restrict__ BTg, float* __restrict__ states){
  int blk = blockIdx.x;
  int nh = blk & 1;
  int r = blk >> 1;
  int h = r % NH;  r /= NH;
  int c = r % NCH;
  int b = r / NCH;
  int tid = threadIdx.x, wave = tid>>6, lane = tid&63, ln = lane&15, quad = lane>>4;
  __shared__ alignas(16) unsigned short As[64*264];
  __shared__ alignas(16) unsigned short Bs[64*264];
  int bh = b*NH + h;
  // stage A: rows p, 512B each (256 k-shorts)
  {
    int srow = tid>>2, sseg = tid&3;
    const unsigned short* ga = Xdec + ((size_t)bh*HD + srow)*SEQ + c*CHUNKC;
    const unsigned short* gb = BTg + ((size_t)b*DSTATE + nh*64 + srow)*SEQ + c*CHUNKC;
    #pragma unroll
    for (int s=0;s<8;s++){
      *(bf16x8*)&As[srow*264 + (sseg+s*4)*8] = *(const bf16x8*)(ga + (sseg+s*4)*8);
      *(bf16x8*)&Bs[srow*264 + (sseg+s*4)*8] = *(const bf16x8*)(gb + (sseg+s*4)*8);
    }
  }
  __syncthreads();
  f32x4 acc[4];
  #pragma unroll
  for (int nt=0;nt<4;nt++) acc[nt] = (f32x4){0.f,0.f,0.f,0.f};
  bf16x8 a[8];
  #pragma unroll
  for (int kq=0;kq<8;kq++)
    a[kq] = *(const bf16x8*)&As[(wave*16+ln)*264 + kq*32 + quad*8];
  #pragma unroll
  for (int nt=0;nt<4;nt++){
    #pragma unroll
    for (int kq=0;kq<8;kq++){
      bf16x8 bb = *(const bf16x8*)&Bs[(nt*16+ln)*264 + kq*32 + quad*8];
      acc[nt] = __builtin_amdgcn_mfma_f32_16x16x32_bf16(a[kq], bb, acc[nt], 0,0,0);
    }
  }
  float* sp = states + (((size_t)(b*NCH+c)*NH + h) << 13) + nh*64;
  #pragma unroll
  for (int nt=0;nt<4;nt++){
    #pragma unroll
    for (int r2=0;r2<4;r2++)
      sp[(size_t)(wave*16 + quad*4 + r2)*DSTATE + nt*16 + ln] = acc[nt][r2];
  }
}

// ---------------- inter-chunk scan ----------------
__global__ __launch_bounds__(256) void ssd_scan(const float* __restrict__ states,
    const float* __restrict__ acs, float* __restrict__ prev){
  int idx = blockIdx.x*256+threadIdx.x;
  if (idx >= BATCH*NH*HD*DSTATE) return;
  int pn = idx & 8191;
  int bh = idx >> 13;
  int h = bh % NH, b = bh / NH;
  float carry = 0.f;
  #pragma unroll
  for (int c=0;c<NCH;c++){
    size_t o = (((size_t)(b*NCH+c)*NH + h) << 13) + pn;
    prev[o] = carry;
    float dec = expf(acs[(b*NH+h)*SEQ + c*CHUNKC + CHUNKC-1]);
    carry = carry*dec + states[o];
  }
}

// ---------------- SSD diag + off-diag + skip via MFMA --------------------------
constexpr int CW_S  = 136;
constexpr int SB_S  = 72;
constexpr int XT_S  = 72;

__global__ __launch_bounds__(256,2) void ssd_diag2(
    const unsigned short* __restrict__ xbcb, const unsigned short* __restrict__ XdT,
    const float* __restrict__ acs, const float* __restrict__ prev,
    const float* __restrict__ dskip, float* __restrict__ Y){
  int blk = blockIdx.x;
  int t = blk & 3;
  int r0 = blk >> 2;
  int h = r0 % NH;  r0 /= NH;
  int c = r0 % NCH;
  int b = r0 / NCH;

  int tid = threadIdx.x;
  int wave = tid>>6, lane = tid&63, ln = lane&15, quad = lane>>4;

  __shared__ float ac[CHUNKC];
  __shared__ alignas(16) unsigned short Cw[64*CW_S];
  __shared__ alignas(16) unsigned short Pv[64*CW_S];
  __shared__ alignas(16) unsigned short Bt[64*CW_S];
  __shared__ alignas(16) unsigned short Xt[64*XT_S];
  __shared__ alignas(16) unsigned short Sb[4][16*SB_S];

  const int bh = b*NH + h;
  const size_t rowbase = (size_t)(b*SEQ + c*CHUNKC);

  ac[tid] = acs[(size_t)bh*SEQ + c*CHUNKC + tid];

  // stage C strip (bf16 direct) and prev (fp32 -> bf16)
  {
    int srow = tid>>2, sseg = tid&3;
    const unsigned short* gc = xbcb + (rowbase + t*64 + srow)*CDIM + DI + DSTATE;
    #pragma unroll
    for (int s=0;s<4;s++)
      *(bf16x8*)&Cw[srow*CW_S + (sseg+s*4)*8] = *(const bf16x8*)(gc + (sseg+s*4)*8);
  }
  {
    const float* pvsrc = prev + (((size_t)(b*NCH+c)*NH + h) << 13);
    for (int idx=tid; idx<2048; idx+=256){
      int row = idx>>5, nq = idx&31;
      float4 w = *(const float4*)(pvsrc + (size_t)row*DSTATE + nq*4);
      ushort4 uw; uw.x=f2bf(w.x); uw.y=f2bf(w.y); uw.z=f2bf(w.z); uw.w=f2bf(w.w);
      *(ushort4*)&Pv[row*CW_S + nq*4] = uw;
    }
  }
  __syncthreads();

  bf16x8 aC[4];
  #pragma unroll
  for (int kq=0;kq<4;kq++)
    aC[kq] = *(const bf16x8*)&Cw[(wave*16+ln)*CW_S + kq*32 + quad*8];

  f32x4 yacc[4];
  #pragma unroll
  for (int ps=0;ps<4;ps++) yacc[ps] = (f32x4){0.f,0.f,0.f,0.f};

  for (int jt=0; jt<=t; jt++){
    __syncthreads();
    // stage B tile (bf16 direct from xbc) and XdT chunk (bf16 direct)
    {
      int srow = tid>>2, sseg = tid&3;
      const unsigned short* gbm = xbcb + (rowbase + jt*64 + srow)*CDIM + DI;
      #pragma unroll
      for (int s=0;s<4;s++)
        *(bf16x8*)&Bt[srow*CW_S + (sseg+s*4)*8] = *(const bf16x8*)(gbm + (sseg+s*4)*8);
      const unsigned short* gx = XdT + ((size_t)bh*HD + srow)*SEQ + c*CHUNKC + jt*64;
      #pragma unroll
      for (int s=0;s<2;s++)
        *(bf16x8*)&Xt[srow*XT_S + (sseg+s*4)*8] = *(const bf16x8*)(gx + (sseg+s*4)*8);
    }
    __syncthreads();

    #pragma unroll
    for (int js=0; js<4; js++){
      f32x4 s = (f32x4){0.f,0.f,0.f,0.f};
      #pragma unroll
      for (int kq=0;kq<4;kq++){
        bf16x8 bB = *(const bf16x8*)&Bt[(js*16+ln)*CW_S + kq*32 + quad*8];
        s = __builtin_amdgcn_mfma_f32_16x16x32_bf16(aC[kq], bB, s, 0,0,0);
      }
      int jc = jt*64 + js*16 + ln;
      #pragma unroll
      for (int r=0;r<4;r++){
        int icl = t*64 + wave*16 + quad*4 + r;
        float d = (jc<=icl) ? (ac[icl]-ac[jc]) : -1e30f;
        Sb[wave][(quad*4+r)*SB_S + js*16 + ln] = f2bf(expf(d)*s[r]);
      }
    }
    bf16x8 aS[2];
    #pragma unroll
    for (int kq=0;kq<2;kq++)
      aS[kq] = *(const bf16x8*)&Sb[wave][ln*SB_S + kq*32 + quad*8];
    #pragma unroll
    for (int ps=0;ps<4;ps++){
      #pragma unroll
      for (int kq=0;kq<2;kq++){
        bf16x8 bX = *(const bf16x8*)&Xt[(ps*16+ln)*XT_S + kq*32 + quad*8];
        yacc[ps] = __builtin_amdgcn_mfma_f32_16x16x32_bf16(aS[kq], bX, yacc[ps], 0,0,0);
      }
    }
  }

  f32x4 oacc[4];
  #pragma unroll
  for (int ps=0;ps<4;ps++) oacc[ps] = (f32x4){0.f,0.f,0.f,0.f};
  #pragma unroll
  for (int ps=0;ps<4;ps++){
    #pragma unroll
    for (int kq=0;kq<4;kq++){
      bf16x8 bP = *(const bf16x8*)&Pv[(ps*16+ln)*CW_S + kq*32 + quad*8];
      oacc[ps] = __builtin_amdgcn_mfma_f32_16x16x32_bf16(aC[kq], bP, oacc[ps], 0,0,0);
    }
  }

  float dsk = dskip[h];
  #pragma unroll
  for (int r=0;r<4;r++){
    int icl = t*64 + wave*16 + quad*4 + r;
    float ei = expf(ac[icl]);
    size_t l = rowbase + icl;
    #pragma unroll
    for (int ps=0;ps<4;ps++){
      int p = ps*16 + ln;
      float xraw = bf2f(xbcb[l*CDIM + h*HD + p]);
      Y[l*DI + h*HD + p] = yacc[ps][r] + ei*oacc[ps][r] + dsk*xraw;
    }
  }
}

// ---------------- gate (silu(z)) + rmsnorm over 1536 -> bf16 ------------
__global__ __launch_bounds__(256) void gate_rms(const unsigned short* __restrict__ zxb,
    const float* __restrict__ gnw, const float* __restrict__ Y,
    unsigned short* __restrict__ Yb){
  int row = blockIdx.x;
  const unsigned short* z = zxb + (size_t)row*PDIM;
  const float* y = Y + (size_t)row*DI;
  float vals[6]; float ss=0.f;
  #pragma unroll
  for (int t=0;t<6;t++){
    int d = threadIdx.x + t*256;
    float v = y[d]*siluf_(bf2f(z[d]));
    vals[t]=v; ss+=v*v;
  }
  __shared__ float red[4];
  float tot = block_sum_256(ss, red);
  float sc = rsqrtf(tot*(1.f/DI)+EPSF);
  #pragma unroll
  for (int t=0;t<6;t++){
    int d = threadIdx.x + t*256;
    Yb[(size_t)row*DI + d] = f2bf(vals[t]*sc*gnw[d]);
  }
}

// ---------------- final pooling + head -----------------------------------------
__global__ __launch_bounds__(256) void mean_pool(const float* __restrict__ hn,
    float* __restrict__ pooled){
  int idx = blockIdx.x*256+threadIdx.x;
  if (idx >= BATCH*DM) return;
  int b = idx / DM, d = idx % DM;
  float s = 0.f;
  for (int l=0;l<SEQ;l++) s += hn[((size_t)(b*SEQ+l))*DM + d];
  pooled[idx] = s * (1.f/SEQ);
}

__global__ __launch_bounds__(512) void head_k(const float* __restrict__ pooled,
    const float* __restrict__ w1, const float* __restrict__ b1,
    const float* __restrict__ g, const float* __restrict__ bb,
    const float* __restrict__ mn, const float* __restrict__ vr,
    const float* __restrict__ w2, const float* __restrict__ b2,
    float* __restrict__ out){
  int b = blockIdx.x;
  int j = threadIdx.x;
  __shared__ float f[512];
  __shared__ float pl[DM];
  for (int t=j; t<DM; t+=512) pl[t] = pooled[b*DM+t];
  __syncthreads();
  float s = b1[j];
  for (int k=0;k<DM;k++) s += pl[k]*w1[k*512+j];
  s = (s-mn[j])*(g[j]*rsqrtf(vr[j]+EPSF)) + bb[j];
  f[j] = fmaxf(s,0.f);
  __syncthreads();
  if (j < 27){
    float o = b2[j];
    for (int k=0;k<512;k++) o += f[k]*w2[k*27+j];
    out[b*27+j] = o;
  }
}

extern "C" void kernel_launch(void* const* d_in, const int* in_sizes, int n_in,
                              void* d_out, int out_size, void* d_ws, size_t ws_size,
                              hipStream_t stream){
  const float* x      = (const float*)d_in[0];
  const float* c1_w   = (const float*)d_in[1];
  const float* c1_b   = (const float*)d_in[2];
  const float* bn1_g  = (const float*)d_in[3];
  const float* bn1_b  = (const float*)d_in[4];
  const float* bn1_m  = (const float*)d_in[5];
  const float* bn1_v  = (const float*)d_in[6];
  const float* c2_w   = (const float*)d_in[7];
  const float* c2_b   = (const float*)d_in[8];
  const float* bn2_g  = (const float*)d_in[9];
  const float* bn2_b  = (const float*)d_in[10];
  const float* bn2_m  = (const float*)d_in[11];
  const float* bn2_v  = (const float*)d_in[12];
  const float* c3_w   = (const float*)d_in[13];
  const float* c3_b   = (const float*)d_in[14];
  const float* bn3_g  = (const float*)d_in[15];
  const float* bn3_b  = (const float*)d_in[16];
  const float* bn3_m  = (const float*)d_in[17];
  const float* bn3_v  = (const float*)d_in[18];
  const float* ln_w   = (const float*)d_in[19];
  const float* inpw   = (const float*)d_in[20];
  const float* convw  = (const float*)d_in[21];
  const float* convb  = (const float*)d_in[22];
  const float* dtb    = (const float*)d_in[23];
  const float* alog   = (const float*)d_in[24];
  const float* dskip  = (const float*)d_in[25];
  const float* gnw    = (const float*)d_in[26];
  const float* outw   = (const float*)d_in[27];
  const float* normfw = (const float*)d_in[28];
  const float* fc1w   = (const float*)d_in[29];
  const float* fc1b   = (const float*)d_in[30];
  const float* bncg   = (const float*)d_in[31];
  const float* bncb   = (const float*)d_in[32];
  const float* bncm   = (const float*)d_in[33];
  const float* bncv   = (const float*)d_in[34];
  const float* fc2w   = (const float*)d_in[35];
  const float* fc2b   = (const float*)d_in[36];
  (void)in_sizes; (void)n_in; (void)out_size; (void)ws_size;

  char* ws = (char*)d_ws;
  size_t off = 0;
  auto alloc = [&](size_t bytes){
    char* p = ws + off;
    off += (bytes + 255) & ~(size_t)255;
    return (void*)p;
  };
  float* h1  = (float*)alloc((size_t)BATCH*192*LS1*4);
  float* h2  = (float*)alloc((size_t)BATCH*384*LS2*4);
  float* h   = (float*)alloc((size_t)BATCH*SEQ*DM*4);
  float* hn  = (float*)alloc((size_t)BATCH*SEQ*DM*4);
  unsigned short* zxb = (unsigned short*)alloc((size_t)BATCH*SEQ*PDIM*2);
  unsigned short* xbcb= (unsigned short*)alloc((size_t)BATCH*SEQ*CDIM*2);
  float* dtt = (float*)alloc((size_t)BATCH*NH*SEQ*4);
  float* acs = (float*)alloc((size_t)BATCH*NH*SEQ*4);
  float* st  = (float*)alloc((size_t)BATCH*NCH*NH*HD*DSTATE*4);
  float* pv  = (float*)alloc((size_t)BATCH*NCH*NH*HD*DSTATE*4);
  float* Y   = (float*)alloc((size_t)BATCH*SEQ*DI*4);
  float* pooled = (float*)alloc((size_t)BATCH*DM*4);
  unsigned short* hnb   = (unsigned short*)alloc((size_t)BATCH*SEQ*DM*2);
  unsigned short* Yb    = (unsigned short*)alloc((size_t)BATCH*SEQ*DI*2);
  unsigned short* wtin  = (unsigned short*)alloc((size_t)PPAD*DM*2);
  unsigned short* wtout = (unsigned short*)alloc((size_t)DM*DI*2);
  unsigned short* XdTg  = (unsigned short*)alloc((size_t)BATCH*NH*HD*SEQ*2);
  unsigned short* Xdecg = (unsigned short*)alloc((size_t)BATCH*NH*HD*SEQ*2);
  unsigned short* BTg   = (unsigned short*)alloc((size_t)BATCH*DSTATE*SEQ*2);

  conv_stem1<<<(BATCH*192*LS1+255)/256,256,0,stream>>>(x, c1_w,c1_b, bn1_g,bn1_b,bn1_m,bn1_v, h1);
  conv_stem2<<<(BATCH*384*LS2+255)/256,256,0,stream>>>(h1, c2_w,c2_b, bn2_g,bn2_b,bn2_m,bn2_v, h2);
  conv_stem3<<<BATCH*768,256,0,stream>>>(h2, c3_w,c3_b, bn3_g,bn3_b,bn3_m,bn3_v, h);

  const int M = BATCH*SEQ;  // 2048
  for (int l=0; l<NLAYER; l++){
    transpose_cvt<<<dim3(PPAD/32, DM/32),256,0,stream>>>(inpw + (size_t)l*DM*PDIM, wtin, DM, PDIM, PPAD);
    transpose_cvt<<<dim3(DM/32, DI/32),256,0,stream>>>(outw + (size_t)l*DI*DM, wtout, DI, DM, DM);

    rmsnorm768<1><<<M,256,0,stream>>>(h, ln_w + (size_t)l*DM, nullptr, hnb);
    gemm_bf16<2><<<dim3(PPAD/128, M/128),256,0,stream>>>(hnb, wtin, nullptr, zxb, PDIM, DM, PDIM);
    dt_scan_p<<<BATCH*NH*NCH,256,0,stream>>>(zxb, dtb + l*NH, alog + l*NH, dtt, acs);
    dwconv<<<(BATCH*SEQ*CDIM+255)/256,256,0,stream>>>(zxb, convw + (size_t)l*CDIM*4, convb + (size_t)l*CDIM, xbcb);
    xprep<<<BATCH*NH*16,256,0,stream>>>(xbcb, dtt, acs, XdTg, Xdecg);
    btprep<<<BATCH*16*2,256,0,stream>>>(xbcb, BTg);
    ssd_states2<<<BATCH*NCH*NH*2,256,0,stream>>>(Xdecg, BTg, st);
    ssd_scan<<<(BATCH*NH*HD*DSTATE+255)/256,256,0,stream>>>(st, acs, pv);
    ssd_diag2<<<BATCH*NCH*NH*4,256,0,stream>>>(xbcb, XdTg, acs, pv, dskip + l*NH, Y);
    gate_rms<<<M,256,0,stream>>>(zxb, gnw + (size_t)l*DI, Y, Yb);
    gemm_acc64<<<dim3(DM/64, M/64),256,0,stream>>>(Yb, wtout, h, DM, DI);
  }

  rmsnorm768<0><<<M,256,0,stream>>>(h, normfw, hn, nullptr);
  mean_pool<<<(BATCH*DM+255)/256,256,0,stream>>>(hn, pooled);
  head_k<<<BATCH,512,0,stream>>>(pooled, fc1w, fc1b, bncg,bncb,bncm,bncv, fc2w, fc2b, (float*)d_out);
}

// Round 6
// 4415.995 us; speedup vs baseline: 6.2861x; 1.0197x over previous
//
#include <hip/hip_runtime.h>
#include <math.h>

#define DEV __device__ __forceinline__

constexpr int BATCH = 2;
constexpr int L0 = 4096;
constexpr int LS1 = 2048;
constexpr int LS2 = 1024;
constexpr int SEQ = 1024;
constexpr int DM = 768;
constexpr int NH = 24;
constexpr int HD = 64;
constexpr int DI = 1536;
constexpr int DSTATE = 128;
constexpr int CDIM = 1792;   // DI + 2*DSTATE
constexpr int PDIM = 3352;   // 2*DI + 2*DSTATE + NH
constexpr int PPAD = 3456;   // PDIM padded to 27*128
constexpr int CHUNKC = 256;
constexpr int NCH = 4;
constexpr int NLAYER = 24;
constexpr float EPSF = 1e-5f;

typedef short bf16x8 __attribute__((ext_vector_type(8)));
typedef float f32x4 __attribute__((ext_vector_type(4)));

DEV float sigmoidf_(float x){ return 1.f/(1.f+expf(-x)); }
DEV float siluf_(float x){ return x*sigmoidf_(x); }
DEV float geluf_(float x){ return 0.5f*x*(1.f+erff(x*0.70710678118654752440f)); }
DEV float softplusf_(float x){ return fmaxf(x,0.f) + log1pf(expf(-fabsf(x))); }

DEV unsigned short f2bf(float x){
  union { float f; unsigned int u; } v; v.f = x;
  unsigned int u = v.u;
  unsigned int r = (u + 0x7fffu + ((u>>16)&1u)) >> 16;
  return (unsigned short)r;
}
DEV float bf2f(unsigned short u){
  union { unsigned int u; float f; } v; v.u = ((unsigned int)u)<<16; return v.f;
}

DEV void load_lds16(const void* g, void* l){
  __builtin_amdgcn_global_load_lds(
      (const __attribute__((address_space(1))) unsigned int*)g,
      (__attribute__((address_space(3))) unsigned int*)l,
      16, 0, 0);
}

DEV float block_sum_256(float v, float* red4){
  #pragma unroll
  for (int o=32;o>0;o>>=1) v += __shfl_down(v,o,64);
  int tid = threadIdx.x;
  __syncthreads();
  if ((tid&63)==0) red4[tid>>6]=v;
  __syncthreads();
  return red4[0]+red4[1]+red4[2]+red4[3];
}

// ---------------- stem ----------------
__global__ __launch_bounds__(256) void conv_stem1(const float* __restrict__ x,
    const float* __restrict__ w, const float* __restrict__ bias,
    const float* __restrict__ g, const float* __restrict__ bb,
    const float* __restrict__ mn, const float* __restrict__ vr,
    float* __restrict__ out){
  int idx = blockIdx.x*256+threadIdx.x;
  if (idx >= BATCH*192*LS1) return;
  int lo = idx & (LS1-1);
  int co = (idx >> 11) % 192;
  int b  = idx / (192*LS1);
  float s = bias[co];
  const float* wr = w + co*60;
  #pragma unroll
  for (int ci=0; ci<12; ci++){
    const float* xr = x + ((size_t)(b*12+ci))*L0;
    #pragma unroll
    for (int k=0;k<5;k++){
      int li = lo*2 + k - 2;
      if (li>=0 && li<L0) s += wr[ci*5+k]*xr[li];
    }
  }
  s = geluf_(s);
  s = (s-mn[co])*(g[co]*rsqrtf(vr[co]+EPSF)) + bb[co];
  out[idx] = s;
}

__global__ __launch_bounds__(256) void conv_stem2(const float* __restrict__ x,
    const float* __restrict__ w, const float* __restrict__ bias,
    const float* __restrict__ g, const float* __restrict__ bb,
    const float* __restrict__ mn, const float* __restrict__ vr,
    float* __restrict__ out){
  int idx = blockIdx.x*256+threadIdx.x;
  if (idx >= BATCH*384*LS2) return;
  int lo = idx & (LS2-1);
  int co = (idx >> 10) % 384;
  int b  = idx / (384*LS2);
  float s = bias[co];
  const float* wr = w + co*(192*3);
  const float* xb = x + (size_t)b*192*LS1;
  for (int ci=0; ci<192; ci++){
    const float* base = xb + ci*LS1;
    int l2 = lo*2;
    s += wr[ci*3+1]*base[l2];
    s += wr[ci*3+2]*base[l2+1];
    if (lo>0) s += wr[ci*3]*base[l2-1];
  }
  s = geluf_(s);
  s = (s-mn[co])*(g[co]*rsqrtf(vr[co]+EPSF)) + bb[co];
  out[idx] = s;
}

__global__ __launch_bounds__(256) void conv_stem3(const float* __restrict__ x,
    const float* __restrict__ w, const float* __restrict__ bias,
    const float* __restrict__ g, const float* __restrict__ bb,
    const float* __restrict__ mn, const float* __restrict__ vr,
    float* __restrict__ h){
  int co = blockIdx.x % 768;
  int b  = blockIdx.x / 768;
  __shared__ float wsh[384*3];
  for (int t=threadIdx.x; t<384*3; t+=256) wsh[t] = w[(size_t)co*1152 + t];
  __syncthreads();
  const float* xb = x + (size_t)b*384*LS2;
  float scale = g[co]*rsqrtf(vr[co]+EPSF);
  float bnb = bb[co], bnm = mn[co], bs0 = bias[co];
  #pragma unroll
  for (int s=0;s<4;s++){
    int lo = s*256 + threadIdx.x;
    int offm = (lo>0)? -1 : 0;        float mm = (lo>0)? 1.f : 0.f;
    int offp = (lo<LS2-1)? 1 : 0;     float mp = (lo<LS2-1)? 1.f : 0.f;
    float acc = bs0;
    for (int ci=0; ci<384; ci++){
      const float* xr = xb + ci*LS2 + lo;
      float w0=wsh[ci*3+0], w1=wsh[ci*3+1], w2=wsh[ci*3+2];
      acc += w1*xr[0];
      acc += mm*w0*xr[offm];
      acc += mp*w2*xr[offp];
    }
    acc = geluf_(acc);
    acc = (acc-bnm)*scale + bnb;
    h[((size_t)(b*SEQ+lo))*DM + co] = acc;
  }
}

// ---------------- rmsnorm (D=768) ----------------
template<int BF>
__global__ __launch_bounds__(256) void rmsnorm768(const float* __restrict__ in,
    const float* __restrict__ w, float* __restrict__ outf, unsigned short* __restrict__ outb){
  int row = blockIdx.x;
  const float* p = in + (size_t)row*DM;
  float v0[3]; float ss=0.f;
  #pragma unroll
  for (int t=0;t<3;t++){ float q = p[threadIdx.x + t*256]; v0[t]=q; ss+=q*q; }
  __shared__ float red[4];
  float tot = block_sum_256(ss, red);
  float sc = rsqrtf(tot*(1.f/DM) + EPSF);
  #pragma unroll
  for (int t=0;t<3;t++){
    int d = threadIdx.x + t*256;
    float o = v0[t]*sc*w[d];
    if (BF) outb[(size_t)row*DM + d] = f2bf(o);
    else    outf[(size_t)row*DM + d] = o;
  }
}

// ------- transpose + fp32->bf16, batched over layers via blockIdx.z ------------
__global__ __launch_bounds__(256) void transpose_cvt_l(const float* __restrict__ in0,
    unsigned short* __restrict__ out0, int R, int Cin, int Cpad,
    size_t in_lstride, size_t out_lstride){
  const float* in = in0 + (size_t)blockIdx.z*in_lstride;
  unsigned short* out = out0 + (size_t)blockIdx.z*out_lstride;
  __shared__ float t[32][33];
  int c0 = blockIdx.x*32, r0 = blockIdx.y*32;
  int tx = threadIdx.x & 31, ty = threadIdx.x >> 5;
  #pragma unroll
  for (int i=0;i<32;i+=8){
    int r = r0+ty+i, c = c0+tx;
    t[ty+i][tx] = (c<Cin) ? in[(size_t)r*Cin + c] : 0.f;
  }
  __syncthreads();
  #pragma unroll
  for (int i=0;i<32;i+=8){
    int c = c0+ty+i, r = r0+tx;
    if (c < Cpad) out[(size_t)c*R + r] = f2bf(t[tx][ty+i]);
  }
}

// ---------------- bf16 MFMA GEMM 128x128 (MODE 2 = bf16 store) -----------------
template<int MODE>
__global__ __launch_bounds__(256,2) void gemm_bf16(const unsigned short* __restrict__ A,
    const unsigned short* __restrict__ Bt, float* __restrict__ Cf,
    unsigned short* __restrict__ Cb, int Ntrue, int K, int ldc){
  __shared__ alignas(16) unsigned short As[128*32];
  __shared__ alignas(16) unsigned short Bs[128*32];
  int tid = threadIdx.x;
  int wave = tid >> 6, lane = tid & 63;
  int mBase = blockIdx.y*128, nBase = blockIdx.x*128;
  const size_t K2 = (size_t)K*2;
  int o0 = wave*1024 + lane*16;
  int o1 = o0 + 4096;
  const char* Ag0 = (const char*)A + (size_t)(mBase + (o0>>6))*K2 + (o0&63);
  const char* Ag1 = (const char*)A + (size_t)(mBase + (o1>>6))*K2 + (o1&63);
  const char* Bg0 = (const char*)Bt + (size_t)(nBase + (o0>>6))*K2 + (o0&63);
  const char* Bg1 = (const char*)Bt + (size_t)(nBase + (o1>>6))*K2 + (o1&63);
  char* AsW = (char*)As + wave*1024;
  char* BsW = (char*)Bs + wave*1024;

  int wm = (wave>>1)*64, wn = (wave&1)*64;
  int ln = lane & 15, quad = lane >> 4;

  f32x4 acc[4][4];
  #pragma unroll
  for (int i=0;i<4;i++)
    #pragma unroll
    for (int j=0;j<4;j++) acc[i][j] = (f32x4){0.f,0.f,0.f,0.f};

  for (int k0=0; k0<K; k0+=32){
    size_t kb = (size_t)k0*2;
    __syncthreads();
    load_lds16(Ag0 + kb, AsW);
    load_lds16(Ag1 + kb, AsW + 4096);
    load_lds16(Bg0 + kb, BsW);
    load_lds16(Bg1 + kb, BsW + 4096);
    __syncthreads();
    bf16x8 a[4], b[4];
    #pragma unroll
    for (int mt=0;mt<4;mt++)
      a[mt] = *(const bf16x8*)((const char*)As + (size_t)(wm+mt*16+ln)*64 + quad*16);
    #pragma unroll
    for (int nt=0;nt<4;nt++)
      b[nt] = *(const bf16x8*)((const char*)Bs + (size_t)(wn+nt*16+ln)*64 + quad*16);
    #pragma unroll
    for (int mt=0;mt<4;mt++)
      #pragma unroll
      for (int nt=0;nt<4;nt++)
        acc[mt][nt] = __builtin_amdgcn_mfma_f32_16x16x32_bf16(a[mt], b[nt], acc[mt][nt], 0,0,0);
  }

  #pragma unroll
  for (int mt=0;mt<4;mt++){
    #pragma unroll
    for (int nt=0;nt<4;nt++){
      int col = nBase + wn + nt*16 + ln;
      int row0 = mBase + wm + mt*16 + quad*4;
      if (col < Ntrue){
        #pragma unroll
        for (int r=0;r<4;r++){
          float v = acc[mt][nt][r];
          if (MODE==2) Cb[(size_t)(row0+r)*ldc + col] = f2bf(v);
          else         Cf[(size_t)(row0+r)*ldc + col] = v;
        }
      }
    }
  }
}

// ---------------- bf16 MFMA GEMM 64x64 tile, BK=128, fp32 accumulate -----------
__global__ __launch_bounds__(256,2) void gemm_acc64(const unsigned short* __restrict__ A,
    const unsigned short* __restrict__ Bt, float* __restrict__ C, int N, int K){
  __shared__ alignas(16) unsigned short As[64*136];
  __shared__ alignas(16) unsigned short Bs[64*136];
  int tid = threadIdx.x;
  int wave = tid>>6, lane = tid&63, ln = lane&15, quad = lane>>4;
  int mBase = blockIdx.y*64, nBase = blockIdx.x*64;
  int srow = tid>>2, sseg = tid&3;
  const unsigned short* Ag = A + (size_t)(mBase+srow)*K;
  const unsigned short* Bg = Bt + (size_t)(nBase+srow)*K;

  f32x4 acc[4];
  #pragma unroll
  for (int nt=0;nt<4;nt++) acc[nt] = (f32x4){0.f,0.f,0.f,0.f};

  for (int k0=0; k0<K; k0+=128){
    __syncthreads();
    #pragma unroll
    for (int s=0;s<4;s++){
      *(bf16x8*)&As[srow*136 + (sseg+s*4)*8] = *(const bf16x8*)(Ag + k0 + (sseg+s*4)*8);
      *(bf16x8*)&Bs[srow*136 + (sseg+s*4)*8] = *(const bf16x8*)(Bg + k0 + (sseg+s*4)*8);
    }
    __syncthreads();
    bf16x8 a[4];
    #pragma unroll
    for (int kq=0;kq<4;kq++)
      a[kq] = *(const bf16x8*)&As[(wave*16+ln)*136 + kq*32 + quad*8];
    #pragma unroll
    for (int nt=0;nt<4;nt++){
      #pragma unroll
      for (int kq=0;kq<4;kq++){
        bf16x8 b = *(const bf16x8*)&Bs[(nt*16+ln)*136 + kq*32 + quad*8];
        acc[nt] = __builtin_amdgcn_mfma_f32_16x16x32_bf16(a[kq], b, acc[nt], 0,0,0);
      }
    }
  }
  #pragma unroll
  for (int nt=0;nt<4;nt++){
    int col = nBase + nt*16 + ln;
    int row0 = mBase + wave*16 + quad*4;
    #pragma unroll
    for (int r=0;r<4;r++){
      float* p = C + (size_t)(row0+r)*N + col;
      *p += acc[nt][r];
    }
  }
}

// ---------------- depthwise causal conv (K=4) + SiLU, vectorized x8 ------------
__global__ __launch_bounds__(256) void dwconv8(const unsigned short* __restrict__ zxb,
    const float* __restrict__ w, const float* __restrict__ bias,
    unsigned short* __restrict__ out){
  int idx = blockIdx.x*256+threadIdx.x;
  if (idx >= BATCH*SEQ*(CDIM/8)) return;
  int c8 = idx % (CDIM/8);
  int l  = (idx/(CDIM/8)) % SEQ;
  int b  = idx / ((CDIM/8)*SEQ);
  int c = c8*8;
  float acc[8];
  #pragma unroll
  for (int j=0;j<8;j++) acc[j] = bias[c+j];
  const unsigned short* colbase = zxb + (size_t)(b*SEQ)*PDIM + DI + c;
  #pragma unroll
  for (int k=0;k<4;k++){
    int li = l-3+k;
    if (li>=0){
      bf16x8 v = *(const bf16x8*)(colbase + (size_t)li*PDIM);
      #pragma unroll
      for (int j=0;j<8;j++) acc[j] += w[(c+j)*4+k]*bf2f((unsigned short)v[j]);
    }
  }
  unsigned short o[8];
  #pragma unroll
  for (int j=0;j<8;j++) o[j] = f2bf(siluf_(acc[j]));
  *(bf16x8*)(out + (size_t)idx*8) = *(bf16x8*)&o[0];
}

// ---------------- fused prep: dt cumsum + XdT/Xdec (blocks 0..191), BT (192..255)
__global__ __launch_bounds__(256) void prep_fused(const unsigned short* __restrict__ zxb,
    const unsigned short* __restrict__ xbcb,
    const float* __restrict__ dtb, const float* __restrict__ alog,
    float* __restrict__ acs, unsigned short* __restrict__ XdT,
    unsigned short* __restrict__ Xdec, unsigned short* __restrict__ BTg){
  int blk = blockIdx.x;
  int tid = threadIdx.x;
  __shared__ alignas(16) unsigned short Xs[64*72];
  __shared__ float sc[256];
  __shared__ float dts[256];
  __shared__ float dec[256];
  if (blk < 192){
    int c = blk % NCH, h = (blk/NCH) % NH, b = blk/(NCH*NH);
    int bh = b*NH + h;
    // phase 1: dt + chunk cumsum
    int l = c*CHUNKC + tid;
    float negA = -expf(alog[h]);
    float lg = bf2f(zxb[((size_t)(b*SEQ+l))*PDIM + (DI+CDIM) + h]) + dtb[h];
    float dt = softplusf_(lg);
    dts[tid] = dt;
    float v = dt*negA;
    sc[tid]=v; __syncthreads();
    #pragma unroll
    for (int off=1; off<256; off<<=1){
      float t = (tid>=off)? sc[tid-off]:0.f;
      __syncthreads();
      v += t; sc[tid]=v;
      __syncthreads();
    }
    acs[(size_t)bh*SEQ + l] = v;
    float aclast = sc[CHUNKC-1];
    dec[tid] = expf(aclast - sc[tid]);
    // phase 2: 4 subtiles of 64 rows -> XdT, Xdec
    int srow = tid>>2, sseg = tid&3;
    int p = tid>>2, lq = tid&3;
    for (int lt2=0; lt2<4; lt2++){
      int lt = c*4 + lt2;
      __syncthreads();
      const unsigned short* src = xbcb + ((size_t)(b*SEQ) + lt*64 + srow)*CDIM + h*HD;
      #pragma unroll
      for (int s=0;s<2;s++)
        *(bf16x8*)&Xs[srow*72 + (sseg+s*4)*8] = *(const bf16x8*)(src + (sseg+s*4)*8);
      __syncthreads();
      unsigned short o1[16], o2[16];
      #pragma unroll
      for (int li=0; li<16; li++){
        int j = lq*16+li;            // row within subtile
        int lc = lt2*64 + j;         // index within chunk
        float vv = bf2f(Xs[j*72 + p]) * dts[lc];
        o1[li] = f2bf(vv);
        o2[li] = f2bf(vv*dec[lc]);
      }
      size_t rowo = ((size_t)bh*HD + p)*SEQ + lt*64 + lq*16;
      *(bf16x8*)(XdT + rowo)     = *(bf16x8*)&o1[0];
      *(bf16x8*)(XdT + rowo + 8) = *(bf16x8*)&o1[8];
      *(bf16x8*)(Xdec + rowo)     = *(bf16x8*)&o2[0];
      *(bf16x8*)(Xdec + rowo + 8) = *(bf16x8*)&o2[8];
    }
  } else {
    int r = blk - 192;
    int nh = r & 1, lt = (r>>1) & 15, b = r >> 5;
    int srow = tid>>2, sseg = tid&3;
    const unsigned short* src = xbcb + ((size_t)(b*SEQ) + lt*64 + srow)*CDIM + DI + nh*64;
    #pragma unroll
    for (int s=0;s<2;s++)
      *(bf16x8*)&Xs[srow*72 + (sseg+s*4)*8] = *(const bf16x8*)(src + (sseg+s*4)*8);
    __syncthreads();
    int n = tid>>2, lq = tid&3;
    unsigned short o[16];
    #pragma unroll
    for (int li=0; li<16; li++) o[li] = Xs[(lq*16+li)*72 + n];
    size_t rowo = ((size_t)b*DSTATE + nh*64 + n)*SEQ + lt*64 + lq*16;
    *(bf16x8*)(BTg + rowo)     = *(bf16x8*)&o[0];
    *(bf16x8*)(BTg + rowo + 8) = *(bf16x8*)&o[8];
  }
}

// ---------------- SSD chunk states: D[p=64][n=64] = Xdec[p][:] . BT[n][:]^T ----
__global__ __launch_bounds__(256) void ssd_states2(const unsigned short* __restrict__ Xdec,
    const unsigned short* __restrict__ BTg, float* __restrict__ states){
  int blk = blockIdx.x;
  int nh = blk & 1;
  int r = blk >> 1;
  int h = r % NH;  r /= NH;
  int c = r % NCH;
  int b = r / NCH;
  int tid = threadIdx.x, wave = tid>>6, lane = tid&63, ln = lane&15, quad = lane>>4;
  __shared__ alignas(16) unsigned short As[64*264];
  __shared__ alignas(16) unsigned short Bs[64*264];
  int bh = b*NH + h;
  {
    int srow = tid>>2, sseg = tid&3;
    const unsigned short* ga = Xdec + ((size_t)bh*HD + srow)*SEQ + c*CHUNKC;
    const unsigned short* gb = BTg + ((size_t)b*DSTATE + nh*64 + srow)*SEQ + c*CHUNKC;
    #pragma unroll
    for (int s=0;s<8;s++){
      *(bf16x8*)&As[srow*264 + (sseg+s*4)*8] = *(const bf16x8*)(ga + (sseg+s*4)*8);
      *(bf16x8*)&Bs[srow*264 + (sseg+s*4)*8] = *(const bf16x8*)(gb + (sseg+s*4)*8);
    }
  }
  __syncthreads();
  f32x4 acc[4];
  #pragma unroll
  for (int nt=0;nt<4;nt++) acc[nt] = (f32x4){0.f,0.f,0.f,0.f};
  bf16x8 a[8];
  #pragma unroll
  for (int kq=0;kq<8;kq++)
    a[kq] = *(const bf16x8*)&As[(wave*16+ln)*264 + kq*32 + quad*8];
  #pragma unroll
  for (int nt=0;nt<4;nt++){
    #pragma unroll
    for (int kq=0;kq<8;kq++){
      bf16x8 bb = *(const bf16x8*)&Bs[(nt*16+ln)*264 + kq*32 + quad*8];
      acc[nt] = __builtin_amdgcn_mfma_f32_16x16x32_bf16(a[kq], bb, acc[nt], 0,0,0);
    }
  }
  float* sp = states + (((size_t)(b*NCH+c)*NH + h) << 13) + nh*64;
  #pragma unroll
  for (int nt=0;nt<4;nt++){
    #pragma unroll
    for (int r2=0;r2<4;r2++)
      sp[(size_t)(wave*16 + quad*4 + r2)*DSTATE + nt*16 + ln] = acc[nt][r2];
  }
}

// ---------------- inter-chunk scan (prev stored bf16) ----------------
__global__ __launch_bounds__(256) void ssd_scan(const float* __restrict__ states,
    const float* __restrict__ acs, unsigned short* __restrict__ prev){
  int idx = blockIdx.x*256+threadIdx.x;
  if (idx >= BATCH*NH*HD*DSTATE) return;
  int pn = idx & 8191;
  int bh = idx >> 13;
  int h = bh % NH, b = bh / NH;
  float carry = 0.f;
  #pragma unroll
  for (int c=0;c<NCH;c++){
    size_t o = (((size_t)(b*NCH+c)*NH + h) << 13) + pn;
    prev[o] = f2bf(carry);
    float dec = expf(acs[(b*NH+h)*SEQ + c*CHUNKC + CHUNKC-1]);
    carry = carry*dec + states[o];
  }
}

// ---------------- SSD diag + off-diag + skip via MFMA --------------------------
constexpr int CW_S  = 136;
constexpr int SB_S  = 72;
constexpr int XT_S  = 72;

__global__ __launch_bounds__(256,2) void ssd_diag2(
    const unsigned short* __restrict__ xbcb, const unsigned short* __restrict__ XdT,
    const float* __restrict__ acs, const unsigned short* __restrict__ prev,
    const float* __restrict__ dskip, unsigned short* __restrict__ Y){
  int blk = blockIdx.x;
  int t = blk & 3;
  int r0 = blk >> 2;
  int h = r0 % NH;  r0 /= NH;
  int c = r0 % NCH;
  int b = r0 / NCH;

  int tid = threadIdx.x;
  int wave = tid>>6, lane = tid&63, ln = lane&15, quad = lane>>4;

  __shared__ float ac[CHUNKC];
  __shared__ alignas(16) unsigned short Cw[64*CW_S];
  __shared__ alignas(16) unsigned short Pv[64*CW_S];
  __shared__ alignas(16) unsigned short Bt[64*CW_S];
  __shared__ alignas(16) unsigned short Xt[64*XT_S];
  __shared__ alignas(16) unsigned short Sb[4][16*SB_S];

  const int bh = b*NH + h;
  const size_t rowbase = (size_t)(b*SEQ + c*CHUNKC);

  ac[tid] = acs[(size_t)bh*SEQ + c*CHUNKC + tid];

  {
    int srow = tid>>2, sseg = tid&3;
    const unsigned short* gc = xbcb + (rowbase + t*64 + srow)*CDIM + DI + DSTATE;
    const unsigned short* gp = prev + (((size_t)(b*NCH+c)*NH + h) << 13) + (size_t)srow*DSTATE;
    #pragma unroll
    for (int s=0;s<4;s++){
      *(bf16x8*)&Cw[srow*CW_S + (sseg+s*4)*8] = *(const bf16x8*)(gc + (sseg+s*4)*8);
      *(bf16x8*)&Pv[srow*CW_S + (sseg+s*4)*8] = *(const bf16x8*)(gp + (sseg+s*4)*8);
    }
  }
  __syncthreads();

  bf16x8 aC[4];
  #pragma unroll
  for (int kq=0;kq<4;kq++)
    aC[kq] = *(const bf16x8*)&Cw[(wave*16+ln)*CW_S + kq*32 + quad*8];

  f32x4 yacc[4];
  #pragma unroll
  for (int ps=0;ps<4;ps++) yacc[ps] = (f32x4){0.f,0.f,0.f,0.f};

  for (int jt=0; jt<=t; jt++){
    __syncthreads();
    {
      int srow = tid>>2, sseg = tid&3;
      const unsigned short* gbm = xbcb + (rowbase + jt*64 + srow)*CDIM + DI;
      #pragma unroll
      for (int s=0;s<4;s++)
        *(bf16x8*)&Bt[srow*CW_S + (sseg+s*4)*8] = *(const bf16x8*)(gbm + (sseg+s*4)*8);
      const unsigned short* gx = XdT + ((size_t)bh*HD + srow)*SEQ + c*CHUNKC + jt*64;
      #pragma unroll
      for (int s=0;s<2;s++)
        *(bf16x8*)&Xt[srow*XT_S + (sseg+s*4)*8] = *(const bf16x8*)(gx + (sseg+s*4)*8);
    }
    __syncthreads();

    #pragma unroll
    for (int js=0; js<4; js++){
      f32x4 s = (f32x4){0.f,0.f,0.f,0.f};
      #pragma unroll
      for (int kq=0;kq<4;kq++){
        bf16x8 bB = *(const bf16x8*)&Bt[(js*16+ln)*CW_S + kq*32 + quad*8];
        s = __builtin_amdgcn_mfma_f32_16x16x32_bf16(aC[kq], bB, s, 0,0,0);
      }
      int jc = jt*64 + js*16 + ln;
      #pragma unroll
      for (int r=0;r<4;r++){
        int icl = t*64 + wave*16 + quad*4 + r;
        float d = (jc<=icl) ? (ac[icl]-ac[jc]) : -1e30f;
        Sb[wave][(quad*4+r)*SB_S + js*16 + ln] = f2bf(expf(d)*s[r]);
      }
    }
    bf16x8 aS[2];
    #pragma unroll
    for (int kq=0;kq<2;kq++)
      aS[kq] = *(const bf16x8*)&Sb[wave][ln*SB_S + kq*32 + quad*8];
    #pragma unroll
    for (int ps=0;ps<4;ps++){
      #pragma unroll
      for (int kq=0;kq<2;kq++){
        bf16x8 bX = *(const bf16x8*)&Xt[(ps*16+ln)*XT_S + kq*32 + quad*8];
        yacc[ps] = __builtin_amdgcn_mfma_f32_16x16x32_bf16(aS[kq], bX, yacc[ps], 0,0,0);
      }
    }
  }

  f32x4 oacc[4];
  #pragma unroll
  for (int ps=0;ps<4;ps++) oacc[ps] = (f32x4){0.f,0.f,0.f,0.f};
  #pragma unroll
  for (int ps=0;ps<4;ps++){
    #pragma unroll
    for (int kq=0;kq<4;kq++){
      bf16x8 bP = *(const bf16x8*)&Pv[(ps*16+ln)*CW_S + kq*32 + quad*8];
      oacc[ps] = __builtin_amdgcn_mfma_f32_16x16x32_bf16(aC[kq], bP, oacc[ps], 0,0,0);
    }
  }

  float dsk = dskip[h];
  #pragma unroll
  for (int r=0;r<4;r++){
    int icl = t*64 + wave*16 + quad*4 + r;
    float ei = expf(ac[icl]);
    size_t l = rowbase + icl;
    #pragma unroll
    for (int ps=0;ps<4;ps++){
      int p = ps*16 + ln;
      float xraw = bf2f(xbcb[l*CDIM + h*HD + p]);
      Y[l*DI + h*HD + p] = f2bf(yacc[ps][r] + ei*oacc[ps][r] + dsk*xraw);
    }
  }
}

// ---------------- gate (silu(z)) + rmsnorm over 1536 -> bf16 ------------
__global__ __launch_bounds__(256) void gate_rms(const unsigned short* __restrict__ zxb,
    const float* __restrict__ gnw, const unsigned short* __restrict__ Y,
    unsigned short* __restrict__ Yb){
  int row = blockIdx.x;
  const unsigned short* z = zxb + (size_t)row*PDIM;
  const unsigned short* y = Y + (size_t)row*DI;
  float vals[6]; float ss=0.f;
  #pragma unroll
  for (int t=0;t<6;t++){
    int d = threadIdx.x + t*256;
    float v = bf2f(y[d])*siluf_(bf2f(z[d]));
    vals[t]=v; ss+=v*v;
  }
  __shared__ float red[4];
  float tot = block_sum_256(ss, red);
  float sc = rsqrtf(tot*(1.f/DI)+EPSF);
  #pragma unroll
  for (int t=0;t<6;t++){
    int d = threadIdx.x + t*256;
    Yb[(size_t)row*DI + d] = f2bf(vals[t]*sc*gnw[d]);
  }
}

// ---------------- final pooling + head -----------------------------------------
__global__ __launch_bounds__(256) void mean_pool(const float* __restrict__ hn,
    float* __restrict__ pooled){
  int idx = blockIdx.x*256+threadIdx.x;
  if (idx >= BATCH*DM) return;
  int b = idx / DM, d = idx % DM;
  float s = 0.f;
  for (int l=0;l<SEQ;l++) s += hn[((size_t)(b*SEQ+l))*DM + d];
  pooled[idx] = s * (1.f/SEQ);
}

__global__ __launch_bounds__(512) void head_k(const float* __restrict__ pooled,
    const float* __restrict__ w1, const float* __restrict__ b1,
    const float* __restrict__ g, const float* __restrict__ bb,
    const float* __restrict__ mn, const float* __restrict__ vr,
    const float* __restrict__ w2, const float* __restrict__ b2,
    float* __restrict__ out){
  int b = blockIdx.x;
  int j = threadIdx.x;
  __shared__ float f[512];
  __shared__ float pl[DM];
  for (int t=j; t<DM; t+=512) pl[t] = pooled[b*DM+t];
  __syncthreads();
  float s = b1[j];
  for (int k=0;k<DM;k++) s += pl[k]*w1[k*512+j];
  s = (s-mn[j])*(g[j]*rsqrtf(vr[j]+EPSF)) + bb[j];
  f[j] = fmaxf(s,0.f);
  __syncthreads();
  if (j < 27){
    float o = b2[j];
    for (int k=0;k<512;k++) o += f[k]*w2[k*27+j];
    out[b*27+j] = o;
  }
}

extern "C" void kernel_launch(void* const* d_in, const int* in_sizes, int n_in,
                              void* d_out, int out_size, void* d_ws, size_t ws_size,
                              hipStream_t stream){
  const float* x      = (const float*)d_in[0];
  const float* c1_w   = (const float*)d_in[1];
  const float* c1_b   = (const float*)d_in[2];
  const float* bn1_g  = (const float*)d_in[3];
  const float* bn1_b  = (const float*)d_in[4];
  const float* bn1_m  = (const float*)d_in[5];
  const float* bn1_v  = (const float*)d_in[6];
  const float* c2_w   = (const float*)d_in[7];
  const float* c2_b   = (const float*)d_in[8];
  const float* bn2_g  = (const float*)d_in[9];
  const float* bn2_b  = (const float*)d_in[10];
  const float* bn2_m  = (const float*)d_in[11];
  const float* bn2_v  = (const float*)d_in[12];
  const float* c3_w   = (const float*)d_in[13];
  const float* c3_b   = (const float*)d_in[14];
  const float* bn3_g  = (const float*)d_in[15];
  const float* bn3_b  = (const float*)d_in[16];
  const float* bn3_m  = (const float*)d_in[17];
  const float* bn3_v  = (const float*)d_in[18];
  const float* ln_w   = (const float*)d_in[19];
  const float* inpw   = (const float*)d_in[20];
  const float* convw  = (const float*)d_in[21];
  const float* convb  = (const float*)d_in[22];
  const float* dtb    = (const float*)d_in[23];
  const float* alog   = (const float*)d_in[24];
  const float* dskip  = (const float*)d_in[25];
  const float* gnw    = (const float*)d_in[26];
  const float* outw   = (const float*)d_in[27];
  const float* normfw = (const float*)d_in[28];
  const float* fc1w   = (const float*)d_in[29];
  const float* fc1b   = (const float*)d_in[30];
  const float* bncg   = (const float*)d_in[31];
  const float* bncb   = (const float*)d_in[32];
  const float* bncm   = (const float*)d_in[33];
  const float* bncv   = (const float*)d_in[34];
  const float* fc2w   = (const float*)d_in[35];
  const float* fc2b   = (const float*)d_in[36];
  (void)in_sizes; (void)n_in; (void)out_size;

  char* ws = (char*)d_ws;
  size_t off = 0;
  auto alloc = [&](size_t bytes){
    char* p = ws + off;
    off += (bytes + 255) & ~(size_t)255;
    return (void*)p;
  };
  float* h1  = (float*)alloc((size_t)BATCH*192*LS1*4);
  float* h2  = (float*)alloc((size_t)BATCH*384*LS2*4);
  float* h   = (float*)alloc((size_t)BATCH*SEQ*DM*4);
  float* hn  = (float*)alloc((size_t)BATCH*SEQ*DM*4);
  unsigned short* zxb = (unsigned short*)alloc((size_t)BATCH*SEQ*PDIM*2);
  unsigned short* xbcb= (unsigned short*)alloc((size_t)BATCH*SEQ*CDIM*2);
  float* acs = (float*)alloc((size_t)BATCH*NH*SEQ*4);
  float* st  = (float*)alloc((size_t)BATCH*NCH*NH*HD*DSTATE*4);
  unsigned short* pv  = (unsigned short*)alloc((size_t)BATCH*NCH*NH*HD*DSTATE*2);
  unsigned short* Y   = (unsigned short*)alloc((size_t)BATCH*SEQ*DI*2);
  float* pooled = (float*)alloc((size_t)BATCH*DM*4);
  unsigned short* hnb   = (unsigned short*)alloc((size_t)BATCH*SEQ*DM*2);
  unsigned short* Yb    = (unsigned short*)alloc((size_t)BATCH*SEQ*DI*2);
  unsigned short* XdTg  = (unsigned short*)alloc((size_t)BATCH*NH*HD*SEQ*2);
  unsigned short* Xdecg = (unsigned short*)alloc((size_t)BATCH*NH*HD*SEQ*2);
  unsigned short* BTg   = (unsigned short*)alloc((size_t)BATCH*DSTATE*SEQ*2);

  // weight buffers: all-layer (hoisted) if ws allows, else per-layer fallback
  const size_t wtin_l  = (size_t)PPAD*DM;     // elems per layer
  const size_t wtout_l = (size_t)DM*DI;
  size_t base_off = off;
  size_t big_bytes = (wtin_l + wtout_l)*NLAYER*2 + 512;
  bool big = (ws_size >= base_off + big_bytes);
  unsigned short *wtinA, *wtoutA;
  if (big){
    wtinA  = (unsigned short*)alloc(wtin_l*NLAYER*2);
    wtoutA = (unsigned short*)alloc(wtout_l*NLAYER*2);
  } else {
    wtinA  = (unsigned short*)alloc(wtin_l*2);
    wtoutA = (unsigned short*)alloc(wtout_l*2);
  }

  if (big){
    transpose_cvt_l<<<dim3(PPAD/32, DM/32, NLAYER),256,0,stream>>>(
        inpw, wtinA, DM, PDIM, PPAD, (size_t)DM*PDIM, wtin_l);
    transpose_cvt_l<<<dim3(DM/32, DI/32, NLAYER),256,0,stream>>>(
        outw, wtoutA, DI, DM, DM, (size_t)DI*DM, wtout_l);
  }

  conv_stem1<<<(BATCH*192*LS1+255)/256,256,0,stream>>>(x, c1_w,c1_b, bn1_g,bn1_b,bn1_m,bn1_v, h1);
  conv_stem2<<<(BATCH*384*LS2+255)/256,256,0,stream>>>(h1, c2_w,c2_b, bn2_g,bn2_b,bn2_m,bn2_v, h2);
  conv_stem3<<<BATCH*768,256,0,stream>>>(h2, c3_w,c3_b, bn3_g,bn3_b,bn3_m,bn3_v, h);

  const int M = BATCH*SEQ;  // 2048
  for (int l=0; l<NLAYER; l++){
    unsigned short* wtin  = big ? (wtinA  + (size_t)l*wtin_l)  : wtinA;
    unsigned short* wtout = big ? (wtoutA + (size_t)l*wtout_l) : wtoutA;
    if (!big){
      transpose_cvt_l<<<dim3(PPAD/32, DM/32, 1),256,0,stream>>>(
          inpw + (size_t)l*DM*PDIM, wtin, DM, PDIM, PPAD, 0, 0);
      transpose_cvt_l<<<dim3(DM/32, DI/32, 1),256,0,stream>>>(
          outw + (size_t)l*DI*DM, wtout, DI, DM, DM, 0, 0);
    }

    rmsnorm768<1><<<M,256,0,stream>>>(h, ln_w + (size_t)l*DM, nullptr, hnb);
    gemm_bf16<2><<<dim3(PPAD/128, M/128),256,0,stream>>>(hnb, wtin, nullptr, zxb, PDIM, DM, PDIM);
    dwconv8<<<(BATCH*SEQ*(CDIM/8)+255)/256,256,0,stream>>>(zxb, convw + (size_t)l*CDIM*4, convb + (size_t)l*CDIM, xbcb);
    prep_fused<<<256,256,0,stream>>>(zxb, xbcb, dtb + l*NH, alog + l*NH, acs, XdTg, Xdecg, BTg);
    ssd_states2<<<BATCH*NCH*NH*2,256,0,stream>>>(Xdecg, BTg, st);
    ssd_scan<<<(BATCH*NH*HD*DSTATE+255)/256,256,0,stream>>>(st, acs, pv);
    ssd_diag2<<<BATCH*NCH*NH*4,256,0,stream>>>(xbcb, XdTg, acs, pv, dskip + l*NH, Y);
    gate_rms<<<M,256,0,stream>>>(zxb, gnw + (size_t)l*DI, Y, Yb);
    gemm_acc64<<<dim3(DM/64, M/64),256,0,stream>>>(Yb, wtout, h, DM, DI);
  }

  rmsnorm768<0><<<M,256,0,stream>>>(h, normfw, hn, nullptr);
  mean_pool<<<(BATCH*DM+255)/256,256,0,stream>>>(hn, pooled);
  head_k<<<BATCH,512,0,stream>>>(pooled, fc1w, fc1b, bncg,bncb,bncm,bncv, fc2w, fc2b, (float*)d_out);
}